// Round 6
// baseline (2321.826 us; speedup 1.0000x reference)
//
#include <hip/hip_runtime.h>
#include <cmath>

namespace {
constexpr int B_ = 16, T_ = 512, P_ = 256, E_ = 128, NB_ = 4, K_ = 4;
constexpr int THREADS_ = 512;
constexpr int RS_ = 132;   // padded ring row stride (floats): rows shift banks by 4

typedef __attribute__((ext_vector_type(8))) short        bf16x8;
typedef __attribute__((ext_vector_type(4))) float        f32x4;
typedef __attribute__((ext_vector_type(4))) unsigned int u32x4;

__device__ __forceinline__ float rcpf(float x) { return __builtin_amdgcn_rcpf(x); }
__device__ __forceinline__ float fast_tanh(float x) {
    float a = fabsf(x);
    float t = __expf(-2.0f * a);
    float r = 1.0f - 2.0f * t * rcpf(1.0f + t);
    return copysignf(r, x);
}

// lgkm-only barrier (R12-proven): orders LDS traffic without draining vmcnt.
__device__ __forceinline__ void lgkm_barrier() {
    __builtin_amdgcn_sched_barrier(0);
    asm volatile("s_waitcnt lgkmcnt(0)\n\ts_barrier" ::: "memory");
    __builtin_amdgcn_sched_barrier(0);
}

// round-to-nearest-even bf16, returned as fp32 bits with low 16 zeroed
__device__ __forceinline__ unsigned bf16rn_hi(float x) {
    const unsigned u = __float_as_uint(x);
    return (u + 0x7FFFu + ((u >> 16) & 1u)) & 0xFFFF0000u;
}
// 3-way RN split of (x,y) into packed bf16 pair planes: x = h+m+l + O(2^-24|x|)
__device__ __forceinline__ void split3_pack(float x, float y,
                                            unsigned &hp, unsigned &mp, unsigned &lp) {
    const unsigned xh = bf16rn_hi(x);
    const float    xr1 = x - __uint_as_float(xh);     // exact (Sterbenz)
    const unsigned xm = bf16rn_hi(xr1);
    const float    xr2 = xr1 - __uint_as_float(xm);   // exact
    const unsigned xl = bf16rn_hi(xr2);
    const unsigned yh = bf16rn_hi(y);
    const float    yr1 = y - __uint_as_float(yh);
    const unsigned ym = bf16rn_hi(yr1);
    const float    yr2 = yr1 - __uint_as_float(ym);
    const unsigned yl = bf16rn_hi(yr2);
    hp = (xh >> 16) | yh;
    mp = (xm >> 16) | ym;
    lp = (xl >> 16) | yl;
}

// ---- cross-lane reductions on the VALU pipe (DPP + permlane)
template<int CTRL>
__device__ __forceinline__ float dpp_addf(float v) {
    const int s = __builtin_amdgcn_update_dpp(0, __float_as_int(v), CTRL, 0xF, 0xF, true);
    return v + __int_as_float(s);
}
template<int Q>
__device__ __forceinline__ float dpp_bcast4(float v) {   // broadcast quad position Q
    const int s = __builtin_amdgcn_update_dpp(0, __float_as_int(v), Q * 0x55, 0xF, 0xF, true);
    return __int_as_float(s);
}
__device__ __forceinline__ float pl16_sum(float v) {     // v + v[lane^16]
#if __has_builtin(__builtin_amdgcn_permlane16_swap)
    const unsigned u = __float_as_uint(v);
    const auto r = __builtin_amdgcn_permlane16_swap(u, u, false, false);
    return __uint_as_float(r[0]) + __uint_as_float(r[1]);
#else
    return v + __shfl_xor(v, 16);
#endif
}
__device__ __forceinline__ float pl32_sum(float v) {     // v + v[lane^32]
#if __has_builtin(__builtin_amdgcn_permlane32_swap)
    const unsigned u = __float_as_uint(v);
    const auto r = __builtin_amdgcn_permlane32_swap(u, u, false, false);
    return __uint_as_float(r[0]) + __uint_as_float(r[1]);
#else
    return v + __shfl_xor(v, 32);
#endif
}
// sum over the 8 kq groups (lane bits 3,4,5)
__device__ __forceinline__ float redkq8(float v) {
    v = dpp_addf<0x128>(v);      // row_ror:8 == xor8 within 16-row
    v = pl16_sum(v);
    v = pl32_sum(v);
    return v;
}
// sum over lane bits 0,1,2 (the 8 pair slots)
__device__ __forceinline__ float redpair(float v) {
    v = dpp_addf<0xB1>(v);       // quad_perm(1,0,3,2) = xor1
    v = dpp_addf<0x4E>(v);       // quad_perm(2,3,0,1) = xor2
    v = dpp_addf<0x141>(v);      // row_half_mirror   = xor7
    return v;
}
// compile-time muxes (no scratch demotion)
__device__ __forceinline__ float sel4(int q, float a, float b, float c, float d) {
    const float t0 = (q & 1) ? b : a;
    const float t1 = (q & 1) ? d : c;
    return (q & 2) ? t1 : t0;
}
__device__ __forceinline__ float sel8f(int kq, float w0, float w1, float w2, float w3,
                                       float w4, float w5, float w6, float w7) {
    const float a = (kq & 1) ? w1 : w0;
    const float b = (kq & 1) ? w3 : w2;
    const float c = (kq & 1) ? w5 : w4;
    const float d = (kq & 1) ? w7 : w6;
    const float e = (kq & 2) ? b : a;
    const float f = (kq & 2) ? d : c;
    return (kq & 4) ? f : e;
}
}

// R14: MFMA matvec with 3-way RN split-bf16 (6 terms: hh, hm+mh, hl+mm+lh).
// Residual ~2^-23 rel -> matvec error ~1e-7, below the fp32-reorder noise of
// the passing VALU kernels (R13's truncation 3-term was ~1e-4 -> jump flips).
// Structure otherwise identical to R12 (passed, 1969us). Wave w's MFMA N-tile
// = its owned e-range [16w,16w+16); D rows 0-3 = bots (reg=bot on all lanes);
// two intra-wave shuffles/bot redistribute to e-pair owners.
__global__ __launch_bounds__(512, 1)
void swarm_ring_kernel(const float* __restrict__ x,            // (B,T,8)
                       const float* __restrict__ W_in,         // (8,E)
                       const float* __restrict__ b_in,         // (E)
                       const float* __restrict__ W_out,        // (E,8)
                       const float* __restrict__ b_out,        // (8)
                       const float* __restrict__ W_p,          // (E,E)
                       const float* __restrict__ b_p,          // (E)
                       const float* __restrict__ ptr_dest,     // (NB,P)
                       const float* __restrict__ jump_W,       // (NB,E)
                       const float* __restrict__ jump_b,       // (NB)
                       const float* __restrict__ ctx_strength, // (NB)
                       const float* __restrict__ phase_bias,   // (NB,E)
                       const float* __restrict__ pointer_init, // (NB,B)
                       float* __restrict__ out)                // (B,T,8)
{
    __shared__ alignas(16) float    ring[P_ * RS_];   // 132 KiB, padded rows
    __shared__ alignas(16) unsigned s1Tp[4][3][68];   // [bot][h/m/l][pair] packed bf16
    __shared__ alignas(16) float    red[32];          // per-wave jump partials
    __shared__ alignas(16) float    hist[16][132];    // ssum history ring
    __shared__ alignas(16) float    wout_s[8][132];   // 0.25 * W_out^T

    const int tid = threadIdx.x;
    const int b   = blockIdx.x;
    const int w   = tid >> 6;
    const int l   = tid & 63;
    const int s_  = l & 7;
    const int kq  = l >> 3;                         // 0..7
    const int e0  = ((w << 3) | s_) << 1;           // owned e-pair: e0, e0+1
    const int pr  = (w << 3) | s_;                  // pair index 0..63
    const int g   = l >> 4;                         // MFMA k-group 0..3
    const int arow = l & 3;                         // A row mod 4 (row r holds bot r&3)
    const int ecol = (w << 4) | (l & 15);           // MFMA N column (e)

    for (int k4 = tid; k4 < P_ * RS_ / 4; k4 += THREADS_)
        ((float4*)ring)[k4] = make_float4(0.f, 0.f, 0.f, 0.f);
    for (int idx = tid; idx < 8 * E_; idx += THREADS_) {
        const int m = idx >> 7, ee = idx & 127;
        wout_s[m][ee] = W_out[ee * 8 + m] * 0.25f;
    }
    for (int i2 = tid; i2 < 4 * 3 * 68; i2 += THREADS_)
        ((unsigned*)s1Tp)[i2] = 0u;

    // ---- B fragments: W_p[k][ecol] 3-way split, k = 32ks + 8g + j (j=0..7)
    bf16x8 bh[4], bm[4], bl[4];
    #pragma unroll
    for (int ks = 0; ks < 4; ++ks) {
        u32x4 uh, um, ul;
        #pragma unroll
        for (int p = 0; p < 4; ++p) {
            const int k0 = 32 * ks + 8 * g + 2 * p;
            const float w0 = W_p[(size_t)k0 * E_ + ecol];
            const float w1 = W_p[(size_t)(k0 + 1) * E_ + ecol];
            unsigned hp, mp, lp;
            split3_pack(w0, w1, hp, mp, lp);
            uh[p] = hp; um[p] = mp; ul[p] = lp;
        }
        bh[ks] = __builtin_bit_cast(bf16x8, uh);
        bm[ks] = __builtin_bit_cast(bf16x8, um);
        bl[ks] = __builtin_bit_cast(bf16x8, ul);
    }

    float2 wi2[8];                                  // W_in[k][e0..e0+1]
    #pragma unroll
    for (int k = 0; k < 8; ++k)
        wi2[k] = *(const float2*)(W_in + k * E_ + e0);

    const float2 bin2 = *(const float2*)(b_in + e0);
    const float  bpc  = b_p[ecol];                  // b_p at MFMA column
    const float  bout_m = b_out[tid & 7];

    float2 pb2[NB_], jw2[NB_], hid2[NB_];
    float  sigc[NB_], jb_r[NB_], ptrv[NB_];
    #pragma unroll
    for (int i = 0; i < NB_; ++i) {
        const float2 pb = *(const float2*)(phase_bias + i * E_ + e0);
        pb2[i] = make_float2(0.1f * pb.x, 0.1f * pb.y);
        jw2[i] = *(const float2*)(jump_W + i * E_ + e0);
        sigc[i] = 1.0f / (1.0f + __expf(-ctx_strength[i]));
        jb_r[i] = jump_b[i];
        hid2[i] = make_float2(0.f, 0.f);
        ptrv[i] = pointer_init[i * B_ + b];
    }

    const float* xb = x + (size_t)b * T_ * 8;
    float xt[8];
    {
        float4 a0 = ((const float4*)xb)[0], a1 = ((const float4*)xb)[1];
        xt[0]=a0.x; xt[1]=a0.y; xt[2]=a0.z; xt[3]=a0.w;
        xt[4]=a1.x; xt[5]=a1.y; xt[6]=a1.z; xt[7]=a1.w;
    }

    const float Cw1 = 0.8824969f, Cw2 = 0.60653066f, Cw3 = 0.32465247f, Cw4 = 0.13533528f;
    const float Dw1 = 0.7788008f, Dw2 = 0.36787944f, Dw3 = 0.105399225f, Dw4 = 0.018315639f;

    __syncthreads();

    for (int t = 0; t < T_; ++t) {
        // ---- geometry, softmax weights, jump-target prefetch (proven math)
        int   baseA[NB_];
        float fA[NB_], psinv[NB_], jt[NB_], wgt[NB_][9];
        #pragma unroll
        for (int i = 0; i < NB_; ++i) {
            const float p = ptrv[i];
            const int base = (int)p;
            baseA[i] = base;
            jt[i] = ptr_dest[i * P_ + base];
            const float f = p - (float)base;
            fA[i] = f;
            const float r  = __expf(0.25f * f);
            const float r2 = r * r, r3 = r2 * r, r4 = r2 * r2;
            const float ri = rcpf(r), ri2 = ri * ri, ri3 = ri2 * ri, ri4 = ri2 * ri2;
            const float p0 = Cw4*ri4, p1 = Cw3*ri3, p2 = Cw2*ri2, p3 = Cw1*ri, p4 = 1.0f,
                        p5 = Cw1*r,  p6 = Cw2*r2,  p7 = Cw3*r3,  p8 = Cw4*r4;
            const float sum = ((p0+p1)+(p2+p3)) + ((p4+p5)+(p6+p7)) + p8;
            const float inv = rcpf(sum);
            psinv[i] = inv;
            wgt[i][0]=p0*inv; wgt[i][1]=p1*inv; wgt[i][2]=p2*inv; wgt[i][3]=p3*inv;
            wgt[i][4]=p4*inv; wgt[i][5]=p5*inv; wgt[i][6]=p6*inv; wgt[i][7]=p7*inv;
            wgt[i][8]=p8*inv;
        }

        // ---- block-uniform independence test
        int ddm[NB_][NB_];
        bool overlap = false;
        #pragma unroll
        for (int j = 1; j < NB_; ++j)
            #pragma unroll
            for (int i = 0; i < j; ++i) {
                const int dd = ((baseA[j] - baseA[i] + 128) & 255) - 128;
                ddm[j][i] = dd;
                overlap = overlap || (dd >= -8 && dd <= 8);
            }

        // ---- gathers: row kq-4 per group (+row +4 on kq0), b64; reduce on VALU
        float  ws[NB_], w8[NB_];
        float2 ctxp2[NB_];
        #pragma unroll
        for (int i = 0; i < NB_; ++i) {
            ws[i] = sel8f(kq, wgt[i][0], wgt[i][1], wgt[i][2], wgt[i][3],
                              wgt[i][4], wgt[i][5], wgt[i][6], wgt[i][7]);
            w8[i] = wgt[i][8];
            const int r0 = (baseA[i] + kq - K_) & (P_ - 1);
            const float2 g0 = *(const float2*)(ring + r0 * RS_ + e0);
            float cx = ws[i] * g0.x;
            float cy = ws[i] * g0.y;
            if (kq == 0) {
                const int r2 = (baseA[i] + K_) & (P_ - 1);
                const float2 g2 = *(const float2*)(ring + r2 * RS_ + e0);
                cx = fmaf(w8[i], g2.x, cx);
                cy = fmaf(w8[i], g2.y, cy);
            }
            ctxp2[i] = make_float2(redkq8(cx), redkq8(cy));
        }

        // ---- inp = x_t @ W_in + b_in (weights in registers)
        float2 inp2 = bin2;
        #pragma unroll
        for (int k = 0; k < 8; ++k) {
            inp2.x = fmaf(xt[k], wi2[k].x, inp2.x);
            inp2.y = fmaf(xt[k], wi2[k].y, inp2.y);
        }

        float xtn[8];
        if (t + 1 < T_) {
            float4 a0 = ((const float4*)(xb + (t + 1) * 8))[0];
            float4 a1 = ((const float4*)(xb + (t + 1) * 8))[1];
            xtn[0]=a0.x; xtn[1]=a0.y; xtn[2]=a0.z; xtn[3]=a0.w;
            xtn[4]=a1.x; xtn[5]=a1.y; xtn[6]=a1.z; xtn[7]=a1.w;
        } else {
            #pragma unroll
            for (int k = 0; k < 8; ++k) xtn[k] = 0.f;
        }

        float2 sv2[NB_];

        if (!overlap) {
            // ================= FAST PATH: all 4 bots independent =================
            float2 s1v[NB_];
            #pragma unroll
            for (int j = 0; j < NB_; ++j) {
                s1v[j].x = fast_tanh(fmaf(sigc[j], ctxp2[j].x, inp2.x + pb2[j].x + hid2[j].x));
                s1v[j].y = fast_tanh(fmaf(sigc[j], ctxp2[j].y, inp2.y + pb2[j].y + hid2[j].y));
            }
            // lane kq<4 splits & writes bot kq's pair (3 planes), conflict-free
            {
                const float sx = sel4(kq, s1v[0].x, s1v[1].x, s1v[2].x, s1v[3].x);
                const float sy = sel4(kq, s1v[0].y, s1v[1].y, s1v[2].y, s1v[3].y);
                unsigned hp, mp, lp;
                split3_pack(sx, sy, hp, mp, lp);
                if (kq < 4) {
                    s1Tp[kq][0][pr] = hp;
                    s1Tp[kq][1][pr] = mp;
                    s1Tp[kq][2][pr] = lp;
                }
            }
            lgkm_barrier();                         // s1 broadcast ready

            f32x4 accA = {0.f,0.f,0.f,0.f}, accB = accA, accC = accA;
            #pragma unroll
            for (int ks = 0; ks < 4; ++ks) {
                const bf16x8 ah = *(const bf16x8*)&s1Tp[arow][0][16 * ks + 4 * g];
                const bf16x8 am = *(const bf16x8*)&s1Tp[arow][1][16 * ks + 4 * g];
                const bf16x8 al = *(const bf16x8*)&s1Tp[arow][2][16 * ks + 4 * g];
                accA = __builtin_amdgcn_mfma_f32_16x16x32_bf16(ah, bh[ks], accA, 0, 0, 0);
                accB = __builtin_amdgcn_mfma_f32_16x16x32_bf16(ah, bm[ks], accB, 0, 0, 0);
                accB = __builtin_amdgcn_mfma_f32_16x16x32_bf16(am, bh[ks], accB, 0, 0, 0);
                accC = __builtin_amdgcn_mfma_f32_16x16x32_bf16(ah, bl[ks], accC, 0, 0, 0);
                accC = __builtin_amdgcn_mfma_f32_16x16x32_bf16(am, bm[ks], accC, 0, 0, 0);
                accC = __builtin_amdgcn_mfma_f32_16x16x32_bf16(al, bh[ks], accC, 0, 0, 0);
            }
            const float t0 = fast_tanh(((accB[0] + accC[0]) + accA[0]) + bpc);
            const float t1 = fast_tanh(((accB[1] + accC[1]) + accA[1]) + bpc);
            const float t2 = fast_tanh(((accB[2] + accC[2]) + accA[2]) + bpc);
            const float t3 = fast_tanh(((accB[3] + accC[3]) + accA[3]) + bpc);
            const int sl0 = s_ << 1, sl1 = sl0 + 1;
            sv2[0] = make_float2(__shfl(t0, sl0), __shfl(t0, sl1));
            sv2[1] = make_float2(__shfl(t1, sl0), __shfl(t1, sl1));
            sv2[2] = make_float2(__shfl(t2, sl0), __shfl(t2, sl1));
            sv2[3] = make_float2(__shfl(t3, sl0), __shfl(t3, sl1));
            #pragma unroll
            for (int j = 0; j < NB_; ++j) hid2[j] = sv2[j];

            // disjoint b64 scatters: lane owns row kq-4 (+row +4 on kq0)
            #pragma unroll
            for (int j = 0; j < NB_; ++j) {
                const float2 s = sv2[j];
                const int r0 = (baseA[j] + kq - K_) & (P_ - 1);
                float2* q0 = (float2*)(ring + r0 * RS_ + e0);
                float2 v0 = *q0;
                v0.x = fmaf(ws[j], s.x, v0.x); v0.y = fmaf(ws[j], s.y, v0.y);
                *q0 = v0;
                if (kq == 0) {
                    const int r2 = (baseA[j] + K_) & (P_ - 1);
                    float2* q2 = (float2*)(ring + r2 * RS_ + e0);
                    float2 v2 = *q2;
                    v2.x = fmaf(w8[j], s.x, v2.x); v2.y = fmaf(w8[j], s.y, v2.y);
                    *q2 = v2;
                }
            }
        } else {
            // ================= SLOW PATH: serial chain with coef corrections =====
            float coefm[NB_][NB_];
            #pragma unroll
            for (int j = 1; j < NB_; ++j) {
                #pragma unroll
                for (int i = 0; i < j; ++i) {
                    const int dd = ddm[j][i];
                    float c = 0.f;
                    if (dd >= -8 && dd <= 8) {
                        const float A = (float)dd - fA[i];
                        const float s  = __expf(-0.25f * (A - fA[j]));
                        const float G  = __expf(0.125f * (fA[i] * fA[i] - A * A));
                        const float s2p = s * s, s3p = s2p * s, s4p = s2p * s2p;
                        const float si = rcpf(s), si2 = si * si, si3 = si2 * si, si4 = si2 * si2;
                        float acc = 0.f;
                        acc += (dd >= 0)              ? Dw4 * si4 : 0.f;
                        acc += (dd >= -1 && dd <= 7)  ? Dw3 * si3 : 0.f;
                        acc += (dd >= -2 && dd <= 6)  ? Dw2 * si2 : 0.f;
                        acc += (dd >= -3 && dd <= 5)  ? Dw1 * si  : 0.f;
                        acc += (dd >= -4 && dd <= 4)  ? 1.0f      : 0.f;
                        acc += (dd >= -5 && dd <= 3)  ? Dw1 * s   : 0.f;
                        acc += (dd >= -6 && dd <= 2)  ? Dw2 * s2p : 0.f;
                        acc += (dd >= -7 && dd <= 1)  ? Dw3 * s3p : 0.f;
                        acc += (dd <= 0)              ? Dw4 * s4p : 0.f;
                        c = psinv[i] * psinv[j] * G * acc;
                    }
                    coefm[j][i] = c;
                }
            }

            #pragma unroll
            for (int j = 0; j < NB_; ++j) {
                float2 ctx = ctxp2[j];
                #pragma unroll
                for (int i = 0; i < j; ++i) {
                    ctx.x = fmaf(coefm[j][i], sv2[i].x, ctx.x);
                    ctx.y = fmaf(coefm[j][i], sv2[i].y, ctx.y);
                }
                float2 s1;
                s1.x = fast_tanh(fmaf(sigc[j], ctx.x, inp2.x + pb2[j].x + hid2[j].x));
                s1.y = fast_tanh(fmaf(sigc[j], ctx.y, inp2.y + pb2[j].y + hid2[j].y));
                {
                    unsigned hp, mp, lp;
                    split3_pack(s1.x, s1.y, hp, mp, lp);
                    if (kq == 0) {
                        s1Tp[j][0][pr] = hp;
                        s1Tp[j][1][pr] = mp;
                        s1Tp[j][2][pr] = lp;
                    }
                }
                lgkm_barrier();                     // s1 row j ready

                f32x4 accA = {0.f,0.f,0.f,0.f}, accB = accA, accC = accA;
                #pragma unroll
                for (int ks = 0; ks < 4; ++ks) {
                    const bf16x8 ah = *(const bf16x8*)&s1Tp[arow][0][16 * ks + 4 * g];
                    const bf16x8 am = *(const bf16x8*)&s1Tp[arow][1][16 * ks + 4 * g];
                    const bf16x8 al = *(const bf16x8*)&s1Tp[arow][2][16 * ks + 4 * g];
                    accA = __builtin_amdgcn_mfma_f32_16x16x32_bf16(ah, bh[ks], accA, 0, 0, 0);
                    accB = __builtin_amdgcn_mfma_f32_16x16x32_bf16(ah, bm[ks], accB, 0, 0, 0);
                    accB = __builtin_amdgcn_mfma_f32_16x16x32_bf16(am, bh[ks], accB, 0, 0, 0);
                    accC = __builtin_amdgcn_mfma_f32_16x16x32_bf16(ah, bl[ks], accC, 0, 0, 0);
                    accC = __builtin_amdgcn_mfma_f32_16x16x32_bf16(am, bm[ks], accC, 0, 0, 0);
                    accC = __builtin_amdgcn_mfma_f32_16x16x32_bf16(al, bh[ks], accC, 0, 0, 0);
                }
                // only D reg j (= bot j on every lane) is meaningful; stale rows harmless
                float tj;
                if (j == 0)      tj = fast_tanh(((accB[0] + accC[0]) + accA[0]) + bpc);
                else if (j == 1) tj = fast_tanh(((accB[1] + accC[1]) + accA[1]) + bpc);
                else if (j == 2) tj = fast_tanh(((accB[2] + accC[2]) + accA[2]) + bpc);
                else             tj = fast_tanh(((accB[3] + accC[3]) + accA[3]) + bpc);
                const int sl0 = s_ << 1;
                float2 s2 = make_float2(__shfl(tj, sl0), __shfl(tj, sl0 + 1));
                sv2[j] = s2; hid2[j] = s2;

                const int r0 = (baseA[j] + kq - K_) & (P_ - 1);
                float2* q0 = (float2*)(ring + r0 * RS_ + e0);
                float2 v0 = *q0;
                v0.x = fmaf(ws[j], s2.x, v0.x); v0.y = fmaf(ws[j], s2.y, v0.y);
                *q0 = v0;
                if (kq == 0) {
                    const int r2 = (baseA[j] + K_) & (P_ - 1);
                    float2* q2 = (float2*)(ring + r2 * RS_ + e0);
                    float2 v2 = *q2;
                    v2.x = fmaf(w8[j], s2.x, v2.x); v2.y = fmaf(w8[j], s2.y, v2.y);
                    *q2 = v2;
                }
            }
        }

        // ---- jump dots: per-lane pair dot, reduce the 8 pair slots on VALU
        {
            float vj0 = fmaf(sv2[0].y, jw2[0].y, sv2[0].x * jw2[0].x);
            float vj1 = fmaf(sv2[1].y, jw2[1].y, sv2[1].x * jw2[1].x);
            float vj2 = fmaf(sv2[2].y, jw2[2].y, sv2[2].x * jw2[2].x);
            float vj3 = fmaf(sv2[3].y, jw2[3].y, sv2[3].x * jw2[3].x);
            vj0 = redpair(vj0); vj1 = redpair(vj1); vj2 = redpair(vj2); vj3 = redpair(vj3);
            if (l == 0)
                ((float4*)red)[w] = make_float4(vj0, vj1, vj2, vj3);
        }

        // ---- ssum -> history ring (kq0 lanes, b64)
        {
            float2 ssum2;
            ssum2.x = (sv2[0].x + sv2[1].x) + (sv2[2].x + sv2[3].x);
            ssum2.y = (sv2[0].y + sv2[1].y) + (sv2[2].y + sv2[3].y);
            if (kq == 0) *(float2*)(&hist[t & 15][e0]) = ssum2;
        }

        lgkm_barrier();                             // red + hist visible

        // ---- zz combine: 1 b32 read + DPP tree (lane l holds red[4w'+bot])
        {
            float rv = red[l & 31];
            rv = dpp_addf<0x124>(rv);               // row_ror:4 -> + same-bot, w'+1
            rv = dpp_addf<0x128>(rv);               // row_ror:8 -> all w' in 16-row
            rv = pl16_sum(rv);                      // + other 16-row
            const float zz0 = dpp_bcast4<0>(rv) + jb_r[0];
            const float zz1 = dpp_bcast4<1>(rv) + jb_r[1];
            const float zz2 = dpp_bcast4<2>(rv) + jb_r[2];
            const float zz3 = dpp_bcast4<3>(rv) + jb_r[3];
            const float zz[4] = { zz0, zz1, zz2, zz3 };
            #pragma unroll
            for (int i = 0; i < NB_; ++i) {
                float np;
                if (zz[i] > 0.0f) np = jt[i];
                else { np = ptrv[i] + 1.0f; if (np >= 256.0f) np -= 256.0f; }
                ptrv[i] = np;
            }
        }

        // ---- every 8th step: 64 threads compute the deferred out dots
        if ((t & 7) == 7 && tid < 64) {
            const int tt = tid >> 3;
            const int m  = tid & 7;
            const float* hrow = hist[(t - 7 + tt) & 15];
            const float* wrow = wout_s[m];
            float acc = 0.f;
            #pragma unroll
            for (int q = 0; q < 32; ++q) {
                const float4 h4 = ((const float4*)hrow)[q];
                const float4 w4 = ((const float4*)wrow)[q];
                acc += ((h4.x * w4.x + h4.y * w4.y) + (h4.z * w4.z + h4.w * w4.w));
            }
            out[((size_t)b * T_ + (t - 7 + tt)) * 8 + m] = acc + bout_m;
        }

        #pragma unroll
        for (int k = 0; k < 8; ++k) xt[k] = xtn[k];
    }
}

extern "C" void kernel_launch(void* const* d_in, const int* in_sizes, int n_in,
                              void* d_out, int out_size, void* d_ws, size_t ws_size,
                              hipStream_t stream) {
    (void)in_sizes; (void)n_in; (void)out_size; (void)d_ws; (void)ws_size;
    swarm_ring_kernel<<<dim3(B_), dim3(THREADS_), 0, stream>>>(
        (const float*)d_in[0],  (const float*)d_in[1],  (const float*)d_in[2],
        (const float*)d_in[3],  (const float*)d_in[4],  (const float*)d_in[5],
        (const float*)d_in[6],  (const float*)d_in[7],  (const float*)d_in[8],
        (const float*)d_in[9],  (const float*)d_in[10], (const float*)d_in[11],
        (const float*)d_in[12], (float*)d_out);
}

// Round 7
// 2193.292 us; speedup vs baseline: 1.0586x; 1.0586x over previous
//
#include <hip/hip_runtime.h>
#include <cmath>

namespace {
constexpr int B_ = 16, T_ = 512, P_ = 256, E_ = 128, NB_ = 4, K_ = 4;
constexpr int THREADS_ = 512;
constexpr int RS_ = 132;   // padded ring row stride (floats): rows shift banks by 4

__device__ __forceinline__ float rcpf(float x) { return __builtin_amdgcn_rcpf(x); }
__device__ __forceinline__ float fast_tanh(float x) {
    float a = fabsf(x);
    float t = __expf(-2.0f * a);
    float r = 1.0f - 2.0f * t * rcpf(1.0f + t);
    return copysignf(r, x);
}

// lgkm-only barrier (R12-proven): orders LDS traffic without draining vmcnt.
__device__ __forceinline__ void lgkm_barrier() {
    __builtin_amdgcn_sched_barrier(0);
    asm volatile("s_waitcnt lgkmcnt(0)\n\ts_barrier" ::: "memory");
    __builtin_amdgcn_sched_barrier(0);
}

// ---- cross-lane reductions on the VALU pipe (DPP + permlane)
template<int CTRL>
__device__ __forceinline__ float dpp_addf(float v) {
    const int s = __builtin_amdgcn_update_dpp(0, __float_as_int(v), CTRL, 0xF, 0xF, true);
    return v + __int_as_float(s);
}
template<int Q>
__device__ __forceinline__ float dpp_bcast4(float v) {   // broadcast quad position Q
    const int s = __builtin_amdgcn_update_dpp(0, __float_as_int(v), Q * 0x55, 0xF, 0xF, true);
    return __int_as_float(s);
}
__device__ __forceinline__ float pl16_sum(float v) {     // v + v[lane^16]
#if __has_builtin(__builtin_amdgcn_permlane16_swap)
    const unsigned u = __float_as_uint(v);
    const auto r = __builtin_amdgcn_permlane16_swap(u, u, false, false);
    return __uint_as_float(r[0]) + __uint_as_float(r[1]);
#else
    return v + __shfl_xor(v, 16);
#endif
}
__device__ __forceinline__ float pl32_sum(float v) {     // v + v[lane^32]
#if __has_builtin(__builtin_amdgcn_permlane32_swap)
    const unsigned u = __float_as_uint(v);
    const auto r = __builtin_amdgcn_permlane32_swap(u, u, false, false);
    return __uint_as_float(r[0]) + __uint_as_float(r[1]);
#else
    return v + __shfl_xor(v, 32);
#endif
}
// sum over the 8 kq groups (lane bits 3,4,5)
__device__ __forceinline__ float redkq8(float v) {
    v = dpp_addf<0x128>(v);      // row_ror:8 == xor8 within 16-row
    v = pl16_sum(v);
    v = pl32_sum(v);
    return v;
}
// sum over lane bits 0,1,2 (the 8 pair slots)
__device__ __forceinline__ float redpair(float v) {
    v = dpp_addf<0xB1>(v);       // quad_perm(1,0,3,2) = xor1
    v = dpp_addf<0x4E>(v);       // quad_perm(2,3,0,1) = xor2
    v = dpp_addf<0x141>(v);      // row_half_mirror   = xor7
    return v;
}
// compile-time mux of 8 values by kq (no scratch demotion)
__device__ __forceinline__ float sel8f(int kq, float w0, float w1, float w2, float w3,
                                       float w4, float w5, float w6, float w7) {
    const float a = (kq & 1) ? w1 : w0;
    const float b = (kq & 1) ? w3 : w2;
    const float c = (kq & 1) ? w5 : w4;
    const float d = (kq & 1) ? w7 : w6;
    const float e = (kq & 2) ? b : a;
    const float f = (kq & 2) ? d : c;
    return (kq & 4) ? f : e;
}
}

// R15: selective-redo slow path on the R12 base (1969us, passing).
// Every step runs the batched fast pipeline (s1 all bots -> 1 barrier ->
// batched matvec). On overlap steps, only bots with a nonzero coef row
// (i.e. overlapping a LOWER-indexed bot) get a serial redo unit
// {ctx+=coef*sv; s1; bcast; barrier; mini-matvec} -- typically 1 unit, not 4.
// All ring scatters + hid/jump/hist move AFTER the redo loop (gathers are
// up-front and coef accounts for intra-step coupling; column e is wave-local
// so per-bot sequential RMWs are ordered). sbuf has 3 slots (j-1 indexed) so
// skipped middle redos can't create a reuse race. Numerically identical
// accumulation order to R12 for both fast and redone bots.
__global__ __launch_bounds__(512, 1)
void swarm_ring_kernel(const float* __restrict__ x,            // (B,T,8)
                       const float* __restrict__ W_in,         // (8,E)
                       const float* __restrict__ b_in,         // (E)
                       const float* __restrict__ W_out,        // (E,8)
                       const float* __restrict__ b_out,        // (8)
                       const float* __restrict__ W_p,          // (E,E)
                       const float* __restrict__ b_p,          // (E)
                       const float* __restrict__ ptr_dest,     // (NB,P)
                       const float* __restrict__ jump_W,       // (NB,E)
                       const float* __restrict__ jump_b,       // (NB)
                       const float* __restrict__ ctx_strength, // (NB)
                       const float* __restrict__ phase_bias,   // (NB,E)
                       const float* __restrict__ pointer_init, // (NB,B)
                       float* __restrict__ out)                // (B,T,8)
{
    __shared__ alignas(16) float  ring[P_ * RS_];   // 132 KiB, padded rows
    __shared__ alignas(16) float4 s4[136];          // fast: s1 4-bot packs, stride 17/16
    __shared__ alignas(16) float  sbuf[3][160];     // redo: s broadcast, pad 4f/16f
    __shared__ alignas(16) float  red[32];          // per-wave jump partials
    __shared__ alignas(16) float  hist[16][132];    // ssum history ring
    __shared__ alignas(16) float  wout_s[8][132];   // 0.25 * W_out^T

    const int tid = threadIdx.x;
    const int b   = blockIdx.x;
    const int w   = tid >> 6;
    const int l   = tid & 63;
    const int s_  = l & 7;
    const int kq  = l >> 3;                         // 0..7
    const int e0  = ((w << 3) | s_) << 1;           // owned e-pair: e0, e0+1

    for (int k4 = tid; k4 < P_ * RS_ / 4; k4 += THREADS_)
        ((float4*)ring)[k4] = make_float4(0.f, 0.f, 0.f, 0.f);
    for (int idx = tid; idx < 8 * E_; idx += THREADS_) {
        const int m = idx >> 7, ee = idx & 127;
        wout_s[m][ee] = W_out[ee * 8 + m] * 0.25f;
    }

    float2 wp2[16];                                 // W_p[16*kq+kk][e0..e0+1]
    #pragma unroll
    for (int kk = 0; kk < 16; ++kk)
        wp2[kk] = *(const float2*)(W_p + (kq * 16 + kk) * E_ + e0);

    float2 wi2[8];                                  // W_in[k][e0..e0+1]
    #pragma unroll
    for (int k = 0; k < 8; ++k)
        wi2[k] = *(const float2*)(W_in + k * E_ + e0);

    const float2 bin2 = *(const float2*)(b_in + e0);
    const float2 bp2  = *(const float2*)(b_p + e0);
    const float  bout_m = b_out[tid & 7];

    float2 pb2[NB_], jw2[NB_], hid2[NB_];
    float  sigc[NB_], jb_r[NB_], ptrv[NB_];
    #pragma unroll
    for (int i = 0; i < NB_; ++i) {
        const float2 pb = *(const float2*)(phase_bias + i * E_ + e0);
        pb2[i] = make_float2(0.1f * pb.x, 0.1f * pb.y);
        jw2[i] = *(const float2*)(jump_W + i * E_ + e0);
        sigc[i] = 1.0f / (1.0f + __expf(-ctx_strength[i]));
        jb_r[i] = jump_b[i];
        hid2[i] = make_float2(0.f, 0.f);
        ptrv[i] = pointer_init[i * B_ + b];
    }

    const float* xb = x + (size_t)b * T_ * 8;
    float xt[8];
    {
        float4 a0 = ((const float4*)xb)[0], a1 = ((const float4*)xb)[1];
        xt[0]=a0.x; xt[1]=a0.y; xt[2]=a0.z; xt[3]=a0.w;
        xt[4]=a1.x; xt[5]=a1.y; xt[6]=a1.z; xt[7]=a1.w;
    }

    const float Cw1 = 0.8824969f, Cw2 = 0.60653066f, Cw3 = 0.32465247f, Cw4 = 0.13533528f;
    const float Dw1 = 0.7788008f, Dw2 = 0.36787944f, Dw3 = 0.105399225f, Dw4 = 0.018315639f;

    __syncthreads();

    for (int t = 0; t < T_; ++t) {
        // ---- geometry, softmax weights, jump-target prefetch (proven math)
        int   baseA[NB_];
        float fA[NB_], psinv[NB_], jt[NB_], wgt[NB_][9];
        #pragma unroll
        for (int i = 0; i < NB_; ++i) {
            const float p = ptrv[i];
            const int base = (int)p;
            baseA[i] = base;
            jt[i] = ptr_dest[i * P_ + base];
            const float f = p - (float)base;
            fA[i] = f;
            const float r  = __expf(0.25f * f);
            const float r2 = r * r, r3 = r2 * r, r4 = r2 * r2;
            const float ri = rcpf(r), ri2 = ri * ri, ri3 = ri2 * ri, ri4 = ri2 * ri2;
            const float p0 = Cw4*ri4, p1 = Cw3*ri3, p2 = Cw2*ri2, p3 = Cw1*ri, p4 = 1.0f,
                        p5 = Cw1*r,  p6 = Cw2*r2,  p7 = Cw3*r3,  p8 = Cw4*r4;
            const float sum = ((p0+p1)+(p2+p3)) + ((p4+p5)+(p6+p7)) + p8;
            const float inv = rcpf(sum);
            psinv[i] = inv;
            wgt[i][0]=p0*inv; wgt[i][1]=p1*inv; wgt[i][2]=p2*inv; wgt[i][3]=p3*inv;
            wgt[i][4]=p4*inv; wgt[i][5]=p5*inv; wgt[i][6]=p6*inv; wgt[i][7]=p7*inv;
            wgt[i][8]=p8*inv;
        }

        // ---- block-uniform independence test + per-bot fix flags
        int ddm[NB_][NB_];
        bool fixrow[NB_] = {false, false, false, false};
        bool overlap = false;
        #pragma unroll
        for (int j = 1; j < NB_; ++j)
            #pragma unroll
            for (int i = 0; i < j; ++i) {
                const int dd = ((baseA[j] - baseA[i] + 128) & 255) - 128;
                ddm[j][i] = dd;
                const bool hit = (dd >= -8 && dd <= 8);
                fixrow[j] = fixrow[j] || hit;
                overlap = overlap || hit;
            }

        // ---- gathers: row kq-4 per group (+row +4 on kq0), b64; reduce on VALU
        float  ws[NB_], w8[NB_];
        float2 ctxp2[NB_];
        #pragma unroll
        for (int i = 0; i < NB_; ++i) {
            ws[i] = sel8f(kq, wgt[i][0], wgt[i][1], wgt[i][2], wgt[i][3],
                              wgt[i][4], wgt[i][5], wgt[i][6], wgt[i][7]);
            w8[i] = wgt[i][8];
            const int r0 = (baseA[i] + kq - K_) & (P_ - 1);
            const float2 g0 = *(const float2*)(ring + r0 * RS_ + e0);
            float cx = ws[i] * g0.x;
            float cy = ws[i] * g0.y;
            if (kq == 0) {
                const int r2 = (baseA[i] + K_) & (P_ - 1);
                const float2 g2 = *(const float2*)(ring + r2 * RS_ + e0);
                cx = fmaf(w8[i], g2.x, cx);
                cy = fmaf(w8[i], g2.y, cy);
            }
            ctxp2[i] = make_float2(redkq8(cx), redkq8(cy));
        }

        // ---- inp = x_t @ W_in + b_in (weights in registers)
        float2 inp2 = bin2;
        #pragma unroll
        for (int k = 0; k < 8; ++k) {
            inp2.x = fmaf(xt[k], wi2[k].x, inp2.x);
            inp2.y = fmaf(xt[k], wi2[k].y, inp2.y);
        }

        float xtn[8];
        if (t + 1 < T_) {
            float4 a0 = ((const float4*)(xb + (t + 1) * 8))[0];
            float4 a1 = ((const float4*)(xb + (t + 1) * 8))[1];
            xtn[0]=a0.x; xtn[1]=a0.y; xtn[2]=a0.z; xtn[3]=a0.w;
            xtn[4]=a1.x; xtn[5]=a1.y; xtn[6]=a1.z; xtn[7]=a1.w;
        } else {
            #pragma unroll
            for (int k = 0; k < 8; ++k) xtn[k] = 0.f;
        }

        float2 sv2[NB_];

        // ============ BATCHED PIPELINE (always): s1 all bots -> 1 barrier
        // ============ -> batched matvec (R12 fast path, scatters deferred)
        {
            float2 s1v[NB_];
            #pragma unroll
            for (int j = 0; j < NB_; ++j) {
                s1v[j].x = fast_tanh(fmaf(sigc[j], ctxp2[j].x, inp2.x + pb2[j].x + hid2[j].x));
                s1v[j].y = fast_tanh(fmaf(sigc[j], ctxp2[j].y, inp2.y + pb2[j].y + hid2[j].y));
            }
            if (kq == 0) {
                const int si = 17 * w + (s_ << 1);   // e0 + (e0>>4)
                s4[si]     = make_float4(s1v[0].x, s1v[1].x, s1v[2].x, s1v[3].x);
                s4[si + 1] = make_float4(s1v[0].y, s1v[1].y, s1v[2].y, s1v[3].y);
            }
            lgkm_barrier();                         // ONE barrier for all 4 broadcasts

            float2 ab0 = make_float2(0.f, 0.f), ab1 = ab0, ab2 = ab0, ab3 = ab0;
            const float4* sp = s4 + kq * 17;        // padded: idx(16kq+kk)=17kq+kk
            #pragma unroll
            for (int kk = 0; kk < 16; ++kk) {
                const float4 sq = sp[kk];
                const float2 w2 = wp2[kk];
                ab0.x = fmaf(sq.x, w2.x, ab0.x); ab0.y = fmaf(sq.x, w2.y, ab0.y);
                ab1.x = fmaf(sq.y, w2.x, ab1.x); ab1.y = fmaf(sq.y, w2.y, ab1.y);
                ab2.x = fmaf(sq.z, w2.x, ab2.x); ab2.y = fmaf(sq.z, w2.y, ab2.y);
                ab3.x = fmaf(sq.w, w2.x, ab3.x); ab3.y = fmaf(sq.w, w2.y, ab3.y);
            }
            sv2[0] = make_float2(fast_tanh(redkq8(ab0.x) + bp2.x), fast_tanh(redkq8(ab0.y) + bp2.y));
            sv2[1] = make_float2(fast_tanh(redkq8(ab1.x) + bp2.x), fast_tanh(redkq8(ab1.y) + bp2.y));
            sv2[2] = make_float2(fast_tanh(redkq8(ab2.x) + bp2.x), fast_tanh(redkq8(ab2.y) + bp2.y));
            sv2[3] = make_float2(fast_tanh(redkq8(ab3.x) + bp2.x), fast_tanh(redkq8(ab3.y) + bp2.y));
        }

        // ============ SELECTIVE REDO: only bots overlapping a lower index
        if (overlap) {
            float coefm[NB_][NB_];
            #pragma unroll
            for (int j = 1; j < NB_; ++j) {
                #pragma unroll
                for (int i = 0; i < j; ++i) {
                    const int dd = ddm[j][i];
                    float c = 0.f;
                    if (dd >= -8 && dd <= 8) {
                        const float A = (float)dd - fA[i];
                        const float s  = __expf(-0.25f * (A - fA[j]));
                        const float G  = __expf(0.125f * (fA[i] * fA[i] - A * A));
                        const float s2p = s * s, s3p = s2p * s, s4p = s2p * s2p;
                        const float si = rcpf(s), si2 = si * si, si3 = si2 * si, si4 = si2 * si2;
                        float acc = 0.f;
                        acc += (dd >= 0)              ? Dw4 * si4 : 0.f;
                        acc += (dd >= -1 && dd <= 7)  ? Dw3 * si3 : 0.f;
                        acc += (dd >= -2 && dd <= 6)  ? Dw2 * si2 : 0.f;
                        acc += (dd >= -3 && dd <= 5)  ? Dw1 * si  : 0.f;
                        acc += (dd >= -4 && dd <= 4)  ? 1.0f      : 0.f;
                        acc += (dd >= -5 && dd <= 3)  ? Dw1 * s   : 0.f;
                        acc += (dd >= -6 && dd <= 2)  ? Dw2 * s2p : 0.f;
                        acc += (dd >= -7 && dd <= 1)  ? Dw3 * s3p : 0.f;
                        acc += (dd <= 0)              ? Dw4 * s4p : 0.f;
                        c = psinv[i] * psinv[j] * G * acc;
                    }
                    coefm[j][i] = c;
                }
            }

            #pragma unroll
            for (int j = 1; j < NB_; ++j) {
                if (fixrow[j]) {                    // block-uniform branch
                    float2 ctx = ctxp2[j];
                    #pragma unroll
                    for (int i = 0; i < j; ++i) {
                        ctx.x = fmaf(coefm[j][i], sv2[i].x, ctx.x);
                        ctx.y = fmaf(coefm[j][i], sv2[i].y, ctx.y);
                    }
                    float2 s1;
                    s1.x = fast_tanh(fmaf(sigc[j], ctx.x, inp2.x + pb2[j].x + hid2[j].x));
                    s1.y = fast_tanh(fmaf(sigc[j], ctx.y, inp2.y + pb2[j].y + hid2[j].y));
                    if (kq == 0) {
                        const int pf = 20 * w + (s_ << 1);   // e0 + 4*(e0>>4)
                        *(float2*)(&sbuf[j - 1][pf]) = s1;
                    }
                    lgkm_barrier();                 // s1 row j ready

                    const float4* sp4 = (const float4*)(&sbuf[j - 1][0]);
                    float ax = 0.f, ay = 0.f;
                    #pragma unroll
                    for (int m = 0; m < 4; ++m) {
                        const float4 sq = sp4[5 * kq + m];   // padded: fidx(4kq+m)=5kq+m
                        const float2 wa = wp2[4*m+0], wb = wp2[4*m+1];
                        const float2 wc = wp2[4*m+2], wd = wp2[4*m+3];
                        ax = fmaf(sq.x, wa.x, ax); ay = fmaf(sq.x, wa.y, ay);
                        ax = fmaf(sq.y, wb.x, ax); ay = fmaf(sq.y, wb.y, ay);
                        ax = fmaf(sq.z, wc.x, ax); ay = fmaf(sq.z, wc.y, ay);
                        ax = fmaf(sq.w, wd.x, ax); ay = fmaf(sq.w, wd.y, ay);
                    }
                    sv2[j].x = fast_tanh(redkq8(ax) + bp2.x);
                    sv2[j].y = fast_tanh(redkq8(ay) + bp2.y);
                }
            }
        }

        // ============ COMMON TAIL: hid update + scatters (final s2 values)
        #pragma unroll
        for (int j = 0; j < NB_; ++j) hid2[j] = sv2[j];

        #pragma unroll
        for (int j = 0; j < NB_; ++j) {
            const float2 s = sv2[j];
            const int r0 = (baseA[j] + kq - K_) & (P_ - 1);
            float2* q0 = (float2*)(ring + r0 * RS_ + e0);
            float2 v0 = *q0;
            v0.x = fmaf(ws[j], s.x, v0.x); v0.y = fmaf(ws[j], s.y, v0.y);
            *q0 = v0;
            if (kq == 0) {
                const int r2 = (baseA[j] + K_) & (P_ - 1);
                float2* q2 = (float2*)(ring + r2 * RS_ + e0);
                float2 v2 = *q2;
                v2.x = fmaf(w8[j], s.x, v2.x); v2.y = fmaf(w8[j], s.y, v2.y);
                *q2 = v2;
            }
        }

        // ---- jump dots: per-lane pair dot, reduce the 8 pair slots on VALU
        {
            float vj0 = fmaf(sv2[0].y, jw2[0].y, sv2[0].x * jw2[0].x);
            float vj1 = fmaf(sv2[1].y, jw2[1].y, sv2[1].x * jw2[1].x);
            float vj2 = fmaf(sv2[2].y, jw2[2].y, sv2[2].x * jw2[2].x);
            float vj3 = fmaf(sv2[3].y, jw2[3].y, sv2[3].x * jw2[3].x);
            vj0 = redpair(vj0); vj1 = redpair(vj1); vj2 = redpair(vj2); vj3 = redpair(vj3);
            if (l == 0)
                ((float4*)red)[w] = make_float4(vj0, vj1, vj2, vj3);
        }

        // ---- ssum -> history ring (kq0 lanes, b64)
        {
            float2 ssum2;
            ssum2.x = (sv2[0].x + sv2[1].x) + (sv2[2].x + sv2[3].x);
            ssum2.y = (sv2[0].y + sv2[1].y) + (sv2[2].y + sv2[3].y);
            if (kq == 0) *(float2*)(&hist[t & 15][e0]) = ssum2;
        }

        lgkm_barrier();                             // scatters + red + hist visible

        // ---- zz combine: 1 b32 read + DPP tree (lane l holds red[4w'+bot])
        {
            float rv = red[l & 31];
            rv = dpp_addf<0x124>(rv);               // row_ror:4 -> + same-bot, w'+1
            rv = dpp_addf<0x128>(rv);               // row_ror:8 -> all w' in 16-row
            rv = pl16_sum(rv);                      // + other 16-row
            const float zz0 = dpp_bcast4<0>(rv) + jb_r[0];
            const float zz1 = dpp_bcast4<1>(rv) + jb_r[1];
            const float zz2 = dpp_bcast4<2>(rv) + jb_r[2];
            const float zz3 = dpp_bcast4<3>(rv) + jb_r[3];
            const float zz[4] = { zz0, zz1, zz2, zz3 };
            #pragma unroll
            for (int i = 0; i < NB_; ++i) {
                float np;
                if (zz[i] > 0.0f) np = jt[i];
                else { np = ptrv[i] + 1.0f; if (np >= 256.0f) np -= 256.0f; }
                ptrv[i] = np;
            }
        }

        // ---- every 8th step: 64 threads compute the deferred out dots
        if ((t & 7) == 7 && tid < 64) {
            const int tt = tid >> 3;
            const int m  = tid & 7;
            const float* hrow = hist[(t - 7 + tt) & 15];
            const float* wrow = wout_s[m];
            float acc = 0.f;
            #pragma unroll
            for (int q = 0; q < 32; ++q) {
                const float4 h4 = ((const float4*)hrow)[q];
                const float4 w4 = ((const float4*)wrow)[q];
                acc += ((h4.x * w4.x + h4.y * w4.y) + (h4.z * w4.z + h4.w * w4.w));
            }
            out[((size_t)b * T_ + (t - 7 + tt)) * 8 + m] = acc + bout_m;
        }

        #pragma unroll
        for (int k = 0; k < 8; ++k) xt[k] = xtn[k];
    }
}

extern "C" void kernel_launch(void* const* d_in, const int* in_sizes, int n_in,
                              void* d_out, int out_size, void* d_ws, size_t ws_size,
                              hipStream_t stream) {
    (void)in_sizes; (void)n_in; (void)out_size; (void)d_ws; (void)ws_size;
    swarm_ring_kernel<<<dim3(B_), dim3(THREADS_), 0, stream>>>(
        (const float*)d_in[0],  (const float*)d_in[1],  (const float*)d_in[2],
        (const float*)d_in[3],  (const float*)d_in[4],  (const float*)d_in[5],
        (const float*)d_in[6],  (const float*)d_in[7],  (const float*)d_in[8],
        (const float*)d_in[9],  (const float*)d_in[10], (const float*)d_in[11],
        (const float*)d_in[12], (float*)d_out);
}

// Round 8
// 1928.430 us; speedup vs baseline: 1.2040x; 1.1373x over previous
//
#include <hip/hip_runtime.h>
#include <cmath>

namespace {
constexpr int B_ = 16, T_ = 512, P_ = 256, E_ = 128, NB_ = 4, K_ = 4;
constexpr int THREADS_ = 512;
constexpr int RS_ = 132;   // padded ring row stride (floats): rows shift banks by 4

__device__ __forceinline__ float rcpf(float x) { return __builtin_amdgcn_rcpf(x); }
__device__ __forceinline__ float fast_tanh(float x) {
    float a = fabsf(x);
    float t = __expf(-2.0f * a);
    float r = 1.0f - 2.0f * t * rcpf(1.0f + t);
    return copysignf(r, x);
}

// lgkm-only barrier (R12-proven): orders LDS traffic without draining vmcnt.
__device__ __forceinline__ void lgkm_barrier() {
    __builtin_amdgcn_sched_barrier(0);
    asm volatile("s_waitcnt lgkmcnt(0)\n\ts_barrier" ::: "memory");
    __builtin_amdgcn_sched_barrier(0);
}

// ---- cross-lane reductions on the VALU pipe (DPP + permlane)
template<int CTRL>
__device__ __forceinline__ float dpp_addf(float v) {
    const int s = __builtin_amdgcn_update_dpp(0, __float_as_int(v), CTRL, 0xF, 0xF, true);
    return v + __int_as_float(s);
}
template<int Q>
__device__ __forceinline__ float dpp_bcast4(float v) {   // broadcast quad position Q
    const int s = __builtin_amdgcn_update_dpp(0, __float_as_int(v), Q * 0x55, 0xF, 0xF, true);
    return __int_as_float(s);
}
template<int Q>
__device__ __forceinline__ int dpp_bcast4i(int v) {      // int variant
    return __builtin_amdgcn_update_dpp(0, v, Q * 0x55, 0xF, 0xF, true);
}
__device__ __forceinline__ float pl16_sum(float v) {     // v + v[lane^16]
#if __has_builtin(__builtin_amdgcn_permlane16_swap)
    const unsigned u = __float_as_uint(v);
    const auto r = __builtin_amdgcn_permlane16_swap(u, u, false, false);
    return __uint_as_float(r[0]) + __uint_as_float(r[1]);
#else
    return v + __shfl_xor(v, 16);
#endif
}
__device__ __forceinline__ float pl32_sum(float v) {     // v + v[lane^32]
#if __has_builtin(__builtin_amdgcn_permlane32_swap)
    const unsigned u = __float_as_uint(v);
    const auto r = __builtin_amdgcn_permlane32_swap(u, u, false, false);
    return __uint_as_float(r[0]) + __uint_as_float(r[1]);
#else
    return v + __shfl_xor(v, 32);
#endif
}
// sum over the 8 kq groups (lane bits 3,4,5)
__device__ __forceinline__ float redkq8(float v) {
    v = dpp_addf<0x128>(v);      // row_ror:8 == xor8 within 16-row
    v = pl16_sum(v);
    v = pl32_sum(v);
    return v;
}
// sum over lane bits 0,1,2 (the 8 pair slots)
__device__ __forceinline__ float redpair(float v) {
    v = dpp_addf<0xB1>(v);       // quad_perm(1,0,3,2) = xor1
    v = dpp_addf<0x4E>(v);       // quad_perm(2,3,0,1) = xor2
    v = dpp_addf<0x141>(v);      // row_half_mirror   = xor7
    return v;
}
// compile-time muxes (no scratch demotion)
__device__ __forceinline__ float sel4(int q, float a, float b, float c, float d) {
    const float t0 = (q & 1) ? b : a;
    const float t1 = (q & 1) ? d : c;
    return (q & 2) ? t1 : t0;
}
__device__ __forceinline__ float sel8f(int kq, float w0, float w1, float w2, float w3,
                                       float w4, float w5, float w6, float w7) {
    const float a = (kq & 1) ? w1 : w0;
    const float b = (kq & 1) ? w3 : w2;
    const float c = (kq & 1) ? w5 : w4;
    const float d = (kq & 1) ? w7 : w6;
    const float e = (kq & 2) ? b : a;
    const float f = (kq & 2) ? d : c;
    return (kq & 4) ? f : e;
}
}

// R16: R12 base (best verified, 1969us rocprof) + quad-parallel geometry.
// The per-step softmax-weight chain (4 bots x ~35 VALU ops incl expf/rcp,
// previously replicated on every lane) is computed once per quad slot:
// lane's quad position bq=l&3 handles bot bq, then quad_perm DPP broadcasts
// (VALU, 1 instr) distribute {ws, w8, jt, base} to all lanes. kq is constant
// within a quad so each lane's own-kq selection broadcasts correctly.
// ptr_dest: 1 load/lane (was 4). Slow path gets fA/psinv via the same
// broadcasts inside the overlap branch. Bit-identical math per bot.
__global__ __launch_bounds__(512, 1)
void swarm_ring_kernel(const float* __restrict__ x,            // (B,T,8)
                       const float* __restrict__ W_in,         // (8,E)
                       const float* __restrict__ b_in,         // (E)
                       const float* __restrict__ W_out,        // (E,8)
                       const float* __restrict__ b_out,        // (8)
                       const float* __restrict__ W_p,          // (E,E)
                       const float* __restrict__ b_p,          // (E)
                       const float* __restrict__ ptr_dest,     // (NB,P)
                       const float* __restrict__ jump_W,       // (NB,E)
                       const float* __restrict__ jump_b,       // (NB)
                       const float* __restrict__ ctx_strength, // (NB)
                       const float* __restrict__ phase_bias,   // (NB,E)
                       const float* __restrict__ pointer_init, // (NB,B)
                       float* __restrict__ out)                // (B,T,8)
{
    __shared__ alignas(16) float  ring[P_ * RS_];   // 132 KiB, padded rows
    __shared__ alignas(16) float4 s4[136];          // fast: s1 4-bot packs, stride 17/16
    __shared__ alignas(16) float  sbuf[2][160];     // slow: s broadcast, pad 4f/16f
    __shared__ alignas(16) float  red[32];          // per-wave jump partials
    __shared__ alignas(16) float  hist[16][132];    // ssum history ring
    __shared__ alignas(16) float  wout_s[8][132];   // 0.25 * W_out^T

    const int tid = threadIdx.x;
    const int b   = blockIdx.x;
    const int w   = tid >> 6;
    const int l   = tid & 63;
    const int s_  = l & 7;
    const int kq  = l >> 3;                         // 0..7
    const int e0  = ((w << 3) | s_) << 1;           // owned e-pair: e0, e0+1
    const int bq  = l & 3;                          // quad slot -> bot index

    for (int k4 = tid; k4 < P_ * RS_ / 4; k4 += THREADS_)
        ((float4*)ring)[k4] = make_float4(0.f, 0.f, 0.f, 0.f);
    for (int idx = tid; idx < 8 * E_; idx += THREADS_) {
        const int m = idx >> 7, ee = idx & 127;
        wout_s[m][ee] = W_out[ee * 8 + m] * 0.25f;
    }

    float2 wp2[16];                                 // W_p[16*kq+kk][e0..e0+1]
    #pragma unroll
    for (int kk = 0; kk < 16; ++kk)
        wp2[kk] = *(const float2*)(W_p + (kq * 16 + kk) * E_ + e0);

    float2 wi2[8];                                  // W_in[k][e0..e0+1]
    #pragma unroll
    for (int k = 0; k < 8; ++k)
        wi2[k] = *(const float2*)(W_in + k * E_ + e0);

    const float2 bin2 = *(const float2*)(b_in + e0);
    const float2 bp2  = *(const float2*)(b_p + e0);
    const float  bout_m = b_out[tid & 7];

    float2 pb2[NB_], jw2[NB_], hid2[NB_];
    float  sigc[NB_], jb_r[NB_], ptrv[NB_];
    #pragma unroll
    for (int i = 0; i < NB_; ++i) {
        const float2 pb = *(const float2*)(phase_bias + i * E_ + e0);
        pb2[i] = make_float2(0.1f * pb.x, 0.1f * pb.y);
        jw2[i] = *(const float2*)(jump_W + i * E_ + e0);
        sigc[i] = 1.0f / (1.0f + __expf(-ctx_strength[i]));
        jb_r[i] = jump_b[i];
        hid2[i] = make_float2(0.f, 0.f);
        ptrv[i] = pointer_init[i * B_ + b];
    }

    const float* xb = x + (size_t)b * T_ * 8;
    float xt[8];
    {
        float4 a0 = ((const float4*)xb)[0], a1 = ((const float4*)xb)[1];
        xt[0]=a0.x; xt[1]=a0.y; xt[2]=a0.z; xt[3]=a0.w;
        xt[4]=a1.x; xt[5]=a1.y; xt[6]=a1.z; xt[7]=a1.w;
    }

    const float Cw1 = 0.8824969f, Cw2 = 0.60653066f, Cw3 = 0.32465247f, Cw4 = 0.13533528f;
    const float Dw1 = 0.7788008f, Dw2 = 0.36787944f, Dw3 = 0.105399225f, Dw4 = 0.018315639f;

    __syncthreads();

    for (int t = 0; t < T_; ++t) {
        // ---- quad-parallel geometry: lane's quad slot bq computes bot bq
        const float p_own    = sel4(bq, ptrv[0], ptrv[1], ptrv[2], ptrv[3]);
        const int   base_own = (int)p_own;
        const float jt_own   = ptr_dest[(bq << 8) + base_own];
        const float f_own    = p_own - (float)base_own;
        float wsel_own, w8_own, psinv_own;
        {
            const float r  = __expf(0.25f * f_own);
            const float r2 = r * r, r3 = r2 * r, r4 = r2 * r2;
            const float ri = rcpf(r), ri2 = ri * ri, ri3 = ri2 * ri, ri4 = ri2 * ri2;
            const float p0 = Cw4*ri4, p1 = Cw3*ri3, p2 = Cw2*ri2, p3 = Cw1*ri, p4c = 1.0f,
                        p5 = Cw1*r,  p6 = Cw2*r2,  p7 = Cw3*r3,  p8 = Cw4*r4;
            const float sum = ((p0+p1)+(p2+p3)) + ((p4c+p5)+(p6+p7)) + p8;
            const float inv = rcpf(sum);
            psinv_own = inv;
            wsel_own = sel8f(kq, p0, p1, p2, p3, p4c, p5, p6, p7) * inv;
            w8_own   = p8 * inv;
        }
        // broadcast bot-q values to all lanes (quad_perm, VALU)
        int   baseA[NB_];
        float jt[NB_], ws[NB_], w8[NB_];
        baseA[0] = dpp_bcast4i<0>(base_own); baseA[1] = dpp_bcast4i<1>(base_own);
        baseA[2] = dpp_bcast4i<2>(base_own); baseA[3] = dpp_bcast4i<3>(base_own);
        jt[0] = dpp_bcast4<0>(jt_own); jt[1] = dpp_bcast4<1>(jt_own);
        jt[2] = dpp_bcast4<2>(jt_own); jt[3] = dpp_bcast4<3>(jt_own);
        ws[0] = dpp_bcast4<0>(wsel_own); ws[1] = dpp_bcast4<1>(wsel_own);
        ws[2] = dpp_bcast4<2>(wsel_own); ws[3] = dpp_bcast4<3>(wsel_own);
        w8[0] = dpp_bcast4<0>(w8_own); w8[1] = dpp_bcast4<1>(w8_own);
        w8[2] = dpp_bcast4<2>(w8_own); w8[3] = dpp_bcast4<3>(w8_own);

        // ---- block-uniform independence test
        int ddm[NB_][NB_];
        bool overlap = false;
        #pragma unroll
        for (int j = 1; j < NB_; ++j)
            #pragma unroll
            for (int i = 0; i < j; ++i) {
                const int dd = ((baseA[j] - baseA[i] + 128) & 255) - 128;
                ddm[j][i] = dd;
                overlap = overlap || (dd >= -8 && dd <= 8);
            }

        // ---- gathers: row kq-4 per group (+row +4 on kq0), b64; reduce on VALU
        float2 ctxp2[NB_];
        #pragma unroll
        for (int i = 0; i < NB_; ++i) {
            const int r0 = (baseA[i] + kq - K_) & (P_ - 1);
            const float2 g0 = *(const float2*)(ring + r0 * RS_ + e0);
            float cx = ws[i] * g0.x;
            float cy = ws[i] * g0.y;
            if (kq == 0) {
                const int r2 = (baseA[i] + K_) & (P_ - 1);
                const float2 g2 = *(const float2*)(ring + r2 * RS_ + e0);
                cx = fmaf(w8[i], g2.x, cx);
                cy = fmaf(w8[i], g2.y, cy);
            }
            ctxp2[i] = make_float2(redkq8(cx), redkq8(cy));
        }

        // ---- inp = x_t @ W_in + b_in (weights in registers)
        float2 inp2 = bin2;
        #pragma unroll
        for (int k = 0; k < 8; ++k) {
            inp2.x = fmaf(xt[k], wi2[k].x, inp2.x);
            inp2.y = fmaf(xt[k], wi2[k].y, inp2.y);
        }

        float xtn[8];
        if (t + 1 < T_) {
            float4 a0 = ((const float4*)(xb + (t + 1) * 8))[0];
            float4 a1 = ((const float4*)(xb + (t + 1) * 8))[1];
            xtn[0]=a0.x; xtn[1]=a0.y; xtn[2]=a0.z; xtn[3]=a0.w;
            xtn[4]=a1.x; xtn[5]=a1.y; xtn[6]=a1.z; xtn[7]=a1.w;
        } else {
            #pragma unroll
            for (int k = 0; k < 8; ++k) xtn[k] = 0.f;
        }

        float2 sv2[NB_];

        if (!overlap) {
            // ================= FAST PATH: all 4 bots independent =================
            float2 s1v[NB_];
            #pragma unroll
            for (int j = 0; j < NB_; ++j) {
                s1v[j].x = fast_tanh(fmaf(sigc[j], ctxp2[j].x, inp2.x + pb2[j].x + hid2[j].x));
                s1v[j].y = fast_tanh(fmaf(sigc[j], ctxp2[j].y, inp2.y + pb2[j].y + hid2[j].y));
            }
            if (kq == 0) {
                const int si = 17 * w + (s_ << 1);   // e0 + (e0>>4)
                s4[si]     = make_float4(s1v[0].x, s1v[1].x, s1v[2].x, s1v[3].x);
                s4[si + 1] = make_float4(s1v[0].y, s1v[1].y, s1v[2].y, s1v[3].y);
            }
            lgkm_barrier();                         // ONE barrier for all 4 broadcasts

            float2 ab0 = make_float2(0.f, 0.f), ab1 = ab0, ab2 = ab0, ab3 = ab0;
            const float4* sp = s4 + kq * 17;        // padded: idx(16kq+kk)=17kq+kk
            #pragma unroll
            for (int kk = 0; kk < 16; ++kk) {
                const float4 sq = sp[kk];
                const float2 w2 = wp2[kk];
                ab0.x = fmaf(sq.x, w2.x, ab0.x); ab0.y = fmaf(sq.x, w2.y, ab0.y);
                ab1.x = fmaf(sq.y, w2.x, ab1.x); ab1.y = fmaf(sq.y, w2.y, ab1.y);
                ab2.x = fmaf(sq.z, w2.x, ab2.x); ab2.y = fmaf(sq.z, w2.y, ab2.y);
                ab3.x = fmaf(sq.w, w2.x, ab3.x); ab3.y = fmaf(sq.w, w2.y, ab3.y);
            }
            sv2[0] = make_float2(fast_tanh(redkq8(ab0.x) + bp2.x), fast_tanh(redkq8(ab0.y) + bp2.y));
            sv2[1] = make_float2(fast_tanh(redkq8(ab1.x) + bp2.x), fast_tanh(redkq8(ab1.y) + bp2.y));
            sv2[2] = make_float2(fast_tanh(redkq8(ab2.x) + bp2.x), fast_tanh(redkq8(ab2.y) + bp2.y));
            sv2[3] = make_float2(fast_tanh(redkq8(ab3.x) + bp2.x), fast_tanh(redkq8(ab3.y) + bp2.y));
            #pragma unroll
            for (int j = 0; j < NB_; ++j) hid2[j] = sv2[j];

            // disjoint b64 scatters: lane owns row kq-4 (+row +4 on kq0)
            #pragma unroll
            for (int j = 0; j < NB_; ++j) {
                const float2 s = sv2[j];
                const int r0 = (baseA[j] + kq - K_) & (P_ - 1);
                float2* q0 = (float2*)(ring + r0 * RS_ + e0);
                float2 v0 = *q0;
                v0.x = fmaf(ws[j], s.x, v0.x); v0.y = fmaf(ws[j], s.y, v0.y);
                *q0 = v0;
                if (kq == 0) {
                    const int r2 = (baseA[j] + K_) & (P_ - 1);
                    float2* q2 = (float2*)(ring + r2 * RS_ + e0);
                    float2 v2 = *q2;
                    v2.x = fmaf(w8[j], s.x, v2.x); v2.y = fmaf(w8[j], s.y, v2.y);
                    *q2 = v2;
                }
            }
        } else {
            // ================= SLOW PATH: serial chain with coef corrections =====
            float fA[NB_], psinv[NB_];
            fA[0] = dpp_bcast4<0>(f_own); fA[1] = dpp_bcast4<1>(f_own);
            fA[2] = dpp_bcast4<2>(f_own); fA[3] = dpp_bcast4<3>(f_own);
            psinv[0] = dpp_bcast4<0>(psinv_own); psinv[1] = dpp_bcast4<1>(psinv_own);
            psinv[2] = dpp_bcast4<2>(psinv_own); psinv[3] = dpp_bcast4<3>(psinv_own);

            float coefm[NB_][NB_];
            #pragma unroll
            for (int j = 1; j < NB_; ++j) {
                #pragma unroll
                for (int i = 0; i < j; ++i) {
                    const int dd = ddm[j][i];
                    float c = 0.f;
                    if (dd >= -8 && dd <= 8) {
                        const float A = (float)dd - fA[i];
                        const float s  = __expf(-0.25f * (A - fA[j]));
                        const float G  = __expf(0.125f * (fA[i] * fA[i] - A * A));
                        const float s2p = s * s, s3p = s2p * s, s4p = s2p * s2p;
                        const float si = rcpf(s), si2 = si * si, si3 = si2 * si, si4 = si2 * si2;
                        float acc = 0.f;
                        acc += (dd >= 0)              ? Dw4 * si4 : 0.f;
                        acc += (dd >= -1 && dd <= 7)  ? Dw3 * si3 : 0.f;
                        acc += (dd >= -2 && dd <= 6)  ? Dw2 * si2 : 0.f;
                        acc += (dd >= -3 && dd <= 5)  ? Dw1 * si  : 0.f;
                        acc += (dd >= -4 && dd <= 4)  ? 1.0f      : 0.f;
                        acc += (dd >= -5 && dd <= 3)  ? Dw1 * s   : 0.f;
                        acc += (dd >= -6 && dd <= 2)  ? Dw2 * s2p : 0.f;
                        acc += (dd >= -7 && dd <= 1)  ? Dw3 * s3p : 0.f;
                        acc += (dd <= 0)              ? Dw4 * s4p : 0.f;
                        c = psinv[i] * psinv[j] * G * acc;
                    }
                    coefm[j][i] = c;
                }
            }

            #pragma unroll
            for (int j = 0; j < NB_; ++j) {
                float2 ctx = ctxp2[j];
                #pragma unroll
                for (int i = 0; i < j; ++i) {
                    ctx.x = fmaf(coefm[j][i], sv2[i].x, ctx.x);
                    ctx.y = fmaf(coefm[j][i], sv2[i].y, ctx.y);
                }
                float2 s1;
                s1.x = fast_tanh(fmaf(sigc[j], ctx.x, inp2.x + pb2[j].x + hid2[j].x));
                s1.y = fast_tanh(fmaf(sigc[j], ctx.y, inp2.y + pb2[j].y + hid2[j].y));
                if (kq == 0) {
                    const int pf = 20 * w + (s_ << 1);   // e0 + 4*(e0>>4)
                    *(float2*)(&sbuf[j & 1][pf]) = s1;
                }
                lgkm_barrier();                     // s broadcast ready

                const float4* sp4 = (const float4*)(&sbuf[j & 1][0]);
                float ax = 0.f, ay = 0.f;
                #pragma unroll
                for (int m = 0; m < 4; ++m) {
                    const float4 sq = sp4[5 * kq + m];   // padded: fidx(4kq+m)=5kq+m
                    const float2 wa = wp2[4*m+0], wb = wp2[4*m+1];
                    const float2 wc = wp2[4*m+2], wd = wp2[4*m+3];
                    ax = fmaf(sq.x, wa.x, ax); ay = fmaf(sq.x, wa.y, ay);
                    ax = fmaf(sq.y, wb.x, ax); ay = fmaf(sq.y, wb.y, ay);
                    ax = fmaf(sq.z, wc.x, ax); ay = fmaf(sq.z, wc.y, ay);
                    ax = fmaf(sq.w, wd.x, ax); ay = fmaf(sq.w, wd.y, ay);
                }
                float2 s2;
                s2.x = fast_tanh(redkq8(ax) + bp2.x);
                s2.y = fast_tanh(redkq8(ay) + bp2.y);
                sv2[j] = s2; hid2[j] = s2;

                const int r0 = (baseA[j] + kq - K_) & (P_ - 1);
                float2* q0 = (float2*)(ring + r0 * RS_ + e0);
                float2 v0 = *q0;
                v0.x = fmaf(ws[j], s2.x, v0.x); v0.y = fmaf(ws[j], s2.y, v0.y);
                *q0 = v0;
                if (kq == 0) {
                    const int r2 = (baseA[j] + K_) & (P_ - 1);
                    float2* q2 = (float2*)(ring + r2 * RS_ + e0);
                    float2 v2 = *q2;
                    v2.x = fmaf(w8[j], s2.x, v2.x); v2.y = fmaf(w8[j], s2.y, v2.y);
                    *q2 = v2;
                }
            }
        }

        // ---- jump dots: per-lane pair dot, reduce the 8 pair slots on VALU
        {
            float vj0 = fmaf(sv2[0].y, jw2[0].y, sv2[0].x * jw2[0].x);
            float vj1 = fmaf(sv2[1].y, jw2[1].y, sv2[1].x * jw2[1].x);
            float vj2 = fmaf(sv2[2].y, jw2[2].y, sv2[2].x * jw2[2].x);
            float vj3 = fmaf(sv2[3].y, jw2[3].y, sv2[3].x * jw2[3].x);
            vj0 = redpair(vj0); vj1 = redpair(vj1); vj2 = redpair(vj2); vj3 = redpair(vj3);
            if (l == 0)
                ((float4*)red)[w] = make_float4(vj0, vj1, vj2, vj3);
        }

        // ---- ssum -> history ring (kq0 lanes, b64)
        {
            float2 ssum2;
            ssum2.x = (sv2[0].x + sv2[1].x) + (sv2[2].x + sv2[3].x);
            ssum2.y = (sv2[0].y + sv2[1].y) + (sv2[2].y + sv2[3].y);
            if (kq == 0) *(float2*)(&hist[t & 15][e0]) = ssum2;
        }

        lgkm_barrier();                             // scatters + red + hist visible

        // ---- zz combine: 1 b32 read + DPP tree (lane l holds red[4w'+bot])
        {
            float rv = red[l & 31];
            rv = dpp_addf<0x124>(rv);               // row_ror:4 -> + same-bot, w'+1
            rv = dpp_addf<0x128>(rv);               // row_ror:8 -> all w' in 16-row
            rv = pl16_sum(rv);                      // + other 16-row
            const float zz0 = dpp_bcast4<0>(rv) + jb_r[0];
            const float zz1 = dpp_bcast4<1>(rv) + jb_r[1];
            const float zz2 = dpp_bcast4<2>(rv) + jb_r[2];
            const float zz3 = dpp_bcast4<3>(rv) + jb_r[3];
            const float zz[4] = { zz0, zz1, zz2, zz3 };
            #pragma unroll
            for (int i = 0; i < NB_; ++i) {
                float np;
                if (zz[i] > 0.0f) np = jt[i];
                else { np = ptrv[i] + 1.0f; if (np >= 256.0f) np -= 256.0f; }
                ptrv[i] = np;
            }
        }

        // ---- every 8th step: 64 threads compute the deferred out dots
        if ((t & 7) == 7 && tid < 64) {
            const int tt = tid >> 3;
            const int m  = tid & 7;
            const float* hrow = hist[(t - 7 + tt) & 15];
            const float* wrow = wout_s[m];
            float acc = 0.f;
            #pragma unroll
            for (int q = 0; q < 32; ++q) {
                const float4 h4 = ((const float4*)hrow)[q];
                const float4 w4 = ((const float4*)wrow)[q];
                acc += ((h4.x * w4.x + h4.y * w4.y) + (h4.z * w4.z + h4.w * w4.w));
            }
            out[((size_t)b * T_ + (t - 7 + tt)) * 8 + m] = acc + bout_m;
        }

        #pragma unroll
        for (int k = 0; k < 8; ++k) xt[k] = xtn[k];
    }
}

extern "C" void kernel_launch(void* const* d_in, const int* in_sizes, int n_in,
                              void* d_out, int out_size, void* d_ws, size_t ws_size,
                              hipStream_t stream) {
    (void)in_sizes; (void)n_in; (void)out_size; (void)d_ws; (void)ws_size;
    swarm_ring_kernel<<<dim3(B_), dim3(THREADS_), 0, stream>>>(
        (const float*)d_in[0],  (const float*)d_in[1],  (const float*)d_in[2],
        (const float*)d_in[3],  (const float*)d_in[4],  (const float*)d_in[5],
        (const float*)d_in[6],  (const float*)d_in[7],  (const float*)d_in[8],
        (const float*)d_in[9],  (const float*)d_in[10], (const float*)d_in[11],
        (const float*)d_in[12], (float*)d_out);
}

// Round 9
// 1902.132 us; speedup vs baseline: 1.2206x; 1.0138x over previous
//
#include <hip/hip_runtime.h>
#include <cmath>

namespace {
constexpr int B_ = 16, T_ = 512, P_ = 256, E_ = 128, NB_ = 4, K_ = 4;
constexpr int THREADS_ = 512;
constexpr int RS_ = 132;   // padded ring row stride (floats): rows shift banks by 4

typedef float v2f __attribute__((ext_vector_type(2)));
__device__ __forceinline__ v2f v2s(float s) { return (v2f){s, s}; }
__device__ __forceinline__ v2f vfma(v2f a, v2f b, v2f c) {
    return __builtin_elementwise_fma(a, b, c);   // -> v_pk_fma_f32 (gfx90a+)
}

__device__ __forceinline__ float rcpf(float x) { return __builtin_amdgcn_rcpf(x); }
__device__ __forceinline__ float fast_tanh(float x) {
    float a = fabsf(x);
    float t = __expf(-2.0f * a);
    float r = 1.0f - 2.0f * t * rcpf(1.0f + t);
    return copysignf(r, x);
}

// lgkm-only barrier (R12-proven): orders LDS traffic without draining vmcnt.
__device__ __forceinline__ void lgkm_barrier() {
    __builtin_amdgcn_sched_barrier(0);
    asm volatile("s_waitcnt lgkmcnt(0)\n\ts_barrier" ::: "memory");
    __builtin_amdgcn_sched_barrier(0);
}

// ---- cross-lane reductions on the VALU pipe (DPP + permlane)
template<int CTRL>
__device__ __forceinline__ float dpp_addf(float v) {
    const int s = __builtin_amdgcn_update_dpp(0, __float_as_int(v), CTRL, 0xF, 0xF, true);
    return v + __int_as_float(s);
}
template<int Q>
__device__ __forceinline__ float dpp_bcast4(float v) {   // broadcast quad position Q
    const int s = __builtin_amdgcn_update_dpp(0, __float_as_int(v), Q * 0x55, 0xF, 0xF, true);
    return __int_as_float(s);
}
template<int Q>
__device__ __forceinline__ int dpp_bcast4i(int v) {      // int variant
    return __builtin_amdgcn_update_dpp(0, v, Q * 0x55, 0xF, 0xF, true);
}
__device__ __forceinline__ float pl16_sum(float v) {     // v + v[lane^16]
#if __has_builtin(__builtin_amdgcn_permlane16_swap)
    const unsigned u = __float_as_uint(v);
    const auto r = __builtin_amdgcn_permlane16_swap(u, u, false, false);
    return __uint_as_float(r[0]) + __uint_as_float(r[1]);
#else
    return v + __shfl_xor(v, 16);
#endif
}
__device__ __forceinline__ float pl32_sum(float v) {     // v + v[lane^32]
#if __has_builtin(__builtin_amdgcn_permlane32_swap)
    const unsigned u = __float_as_uint(v);
    const auto r = __builtin_amdgcn_permlane32_swap(u, u, false, false);
    return __uint_as_float(r[0]) + __uint_as_float(r[1]);
#else
    return v + __shfl_xor(v, 32);
#endif
}
// sum over the 8 kq groups (lane bits 3,4,5)
__device__ __forceinline__ float redkq8(float v) {
    v = dpp_addf<0x128>(v);      // row_ror:8 == xor8 within 16-row
    v = pl16_sum(v);
    v = pl32_sum(v);
    return v;
}
// sum over lane bits 0,1,2 (the 8 pair slots)
__device__ __forceinline__ float redpair(float v) {
    v = dpp_addf<0xB1>(v);       // quad_perm(1,0,3,2) = xor1
    v = dpp_addf<0x4E>(v);       // quad_perm(2,3,0,1) = xor2
    v = dpp_addf<0x141>(v);      // row_half_mirror   = xor7
    return v;
}
// compile-time muxes (no scratch demotion)
__device__ __forceinline__ float sel4(int q, float a, float b, float c, float d) {
    const float t0 = (q & 1) ? b : a;
    const float t1 = (q & 1) ? d : c;
    return (q & 2) ? t1 : t0;
}
__device__ __forceinline__ float sel8f(int kq, float w0, float w1, float w2, float w3,
                                       float w4, float w5, float w6, float w7) {
    const float a = (kq & 1) ? w1 : w0;
    const float b = (kq & 1) ? w3 : w2;
    const float c = (kq & 1) ? w5 : w4;
    const float d = (kq & 1) ? w7 : w6;
    const float e = (kq & 2) ? b : a;
    const float f = (kq & 2) ? d : c;
    return (kq & 4) ? f : e;
}
}

// R17: R16 base (best: 1879us rocprof) + packed-fp32 math + spread out-dots.
//  - all scalar-x-pair FMA blocks (W_p matvec 128->64, inp 16->8, gathers,
//    scatters, ctx corrections, pre-adds) rewritten on ext_vector float2 with
//    __builtin_elementwise_fma -> v_pk_fma_f32; splat multiplier folds to
//    op_sel. Per-element op order identical -> bit-identical numerics.
//  - every-8th-step out-dots spread over all 8 waves (8 lanes/dot + redpair)
//    instead of 128 serial FMAs on wave 0 (removes the straggler).
__global__ __launch_bounds__(512, 1)
void swarm_ring_kernel(const float* __restrict__ x,            // (B,T,8)
                       const float* __restrict__ W_in,         // (8,E)
                       const float* __restrict__ b_in,         // (E)
                       const float* __restrict__ W_out,        // (E,8)
                       const float* __restrict__ b_out,        // (8)
                       const float* __restrict__ W_p,          // (E,E)
                       const float* __restrict__ b_p,          // (E)
                       const float* __restrict__ ptr_dest,     // (NB,P)
                       const float* __restrict__ jump_W,       // (NB,E)
                       const float* __restrict__ jump_b,       // (NB)
                       const float* __restrict__ ctx_strength, // (NB)
                       const float* __restrict__ phase_bias,   // (NB,E)
                       const float* __restrict__ pointer_init, // (NB,B)
                       float* __restrict__ out)                // (B,T,8)
{
    __shared__ alignas(16) float  ring[P_ * RS_];   // 132 KiB, padded rows
    __shared__ alignas(16) float4 s4[136];          // fast: s1 4-bot packs, stride 17/16
    __shared__ alignas(16) float  sbuf[2][160];     // slow: s broadcast, pad 4f/16f
    __shared__ alignas(16) float  red[32];          // per-wave jump partials
    __shared__ alignas(16) float  hist[16][132];    // ssum history ring
    __shared__ alignas(16) float  wout_s[8][132];   // 0.25 * W_out^T

    const int tid = threadIdx.x;
    const int b   = blockIdx.x;
    const int w   = tid >> 6;
    const int l   = tid & 63;
    const int s_  = l & 7;
    const int kq  = l >> 3;                         // 0..7
    const int e0  = ((w << 3) | s_) << 1;           // owned e-pair: e0, e0+1
    const int bq  = l & 3;                          // quad slot -> bot index

    for (int k4 = tid; k4 < P_ * RS_ / 4; k4 += THREADS_)
        ((float4*)ring)[k4] = make_float4(0.f, 0.f, 0.f, 0.f);
    for (int idx = tid; idx < 8 * E_; idx += THREADS_) {
        const int m = idx >> 7, ee = idx & 127;
        wout_s[m][ee] = W_out[ee * 8 + m] * 0.25f;
    }

    v2f wp2[16];                                    // W_p[16*kq+kk][e0..e0+1]
    #pragma unroll
    for (int kk = 0; kk < 16; ++kk)
        wp2[kk] = *(const v2f*)(W_p + (kq * 16 + kk) * E_ + e0);

    v2f wi2[8];                                     // W_in[k][e0..e0+1]
    #pragma unroll
    for (int k = 0; k < 8; ++k)
        wi2[k] = *(const v2f*)(W_in + k * E_ + e0);

    const v2f bin2 = *(const v2f*)(b_in + e0);
    const v2f bp2  = *(const v2f*)(b_p + e0);
    const float bout_m = b_out[tid & 7];

    v2f   pb2[NB_], jw2[NB_], hid2[NB_];
    float sigc[NB_], jb_r[NB_], ptrv[NB_];
    #pragma unroll
    for (int i = 0; i < NB_; ++i) {
        const v2f pb = *(const v2f*)(phase_bias + i * E_ + e0);
        pb2[i] = 0.1f * pb;
        jw2[i] = *(const v2f*)(jump_W + i * E_ + e0);
        sigc[i] = 1.0f / (1.0f + __expf(-ctx_strength[i]));
        jb_r[i] = jump_b[i];
        hid2[i] = (v2f){0.f, 0.f};
        ptrv[i] = pointer_init[i * B_ + b];
    }

    const float* xb = x + (size_t)b * T_ * 8;
    float xt[8];
    {
        float4 a0 = ((const float4*)xb)[0], a1 = ((const float4*)xb)[1];
        xt[0]=a0.x; xt[1]=a0.y; xt[2]=a0.z; xt[3]=a0.w;
        xt[4]=a1.x; xt[5]=a1.y; xt[6]=a1.z; xt[7]=a1.w;
    }

    const float Cw1 = 0.8824969f, Cw2 = 0.60653066f, Cw3 = 0.32465247f, Cw4 = 0.13533528f;
    const float Dw1 = 0.7788008f, Dw2 = 0.36787944f, Dw3 = 0.105399225f, Dw4 = 0.018315639f;

    __syncthreads();

    for (int t = 0; t < T_; ++t) {
        // ---- quad-parallel geometry: lane's quad slot bq computes bot bq
        const float p_own    = sel4(bq, ptrv[0], ptrv[1], ptrv[2], ptrv[3]);
        const int   base_own = (int)p_own;
        const float jt_own   = ptr_dest[(bq << 8) + base_own];
        const float f_own    = p_own - (float)base_own;
        float wsel_own, w8_own, psinv_own;
        {
            const float r  = __expf(0.25f * f_own);
            const float r2 = r * r, r3 = r2 * r, r4 = r2 * r2;
            const float ri = rcpf(r), ri2 = ri * ri, ri3 = ri2 * ri, ri4 = ri2 * ri2;
            const float p0 = Cw4*ri4, p1 = Cw3*ri3, p2 = Cw2*ri2, p3 = Cw1*ri, p4c = 1.0f,
                        p5 = Cw1*r,  p6 = Cw2*r2,  p7 = Cw3*r3,  p8 = Cw4*r4;
            const float sum = ((p0+p1)+(p2+p3)) + ((p4c+p5)+(p6+p7)) + p8;
            const float inv = rcpf(sum);
            psinv_own = inv;
            wsel_own = sel8f(kq, p0, p1, p2, p3, p4c, p5, p6, p7) * inv;
            w8_own   = p8 * inv;
        }
        // broadcast bot-q values to all lanes (quad_perm, VALU)
        int   baseA[NB_];
        float jt[NB_], ws[NB_], w8[NB_];
        baseA[0] = dpp_bcast4i<0>(base_own); baseA[1] = dpp_bcast4i<1>(base_own);
        baseA[2] = dpp_bcast4i<2>(base_own); baseA[3] = dpp_bcast4i<3>(base_own);
        jt[0] = dpp_bcast4<0>(jt_own); jt[1] = dpp_bcast4<1>(jt_own);
        jt[2] = dpp_bcast4<2>(jt_own); jt[3] = dpp_bcast4<3>(jt_own);
        ws[0] = dpp_bcast4<0>(wsel_own); ws[1] = dpp_bcast4<1>(wsel_own);
        ws[2] = dpp_bcast4<2>(wsel_own); ws[3] = dpp_bcast4<3>(wsel_own);
        w8[0] = dpp_bcast4<0>(w8_own); w8[1] = dpp_bcast4<1>(w8_own);
        w8[2] = dpp_bcast4<2>(w8_own); w8[3] = dpp_bcast4<3>(w8_own);

        // ---- block-uniform independence test
        int ddm[NB_][NB_];
        bool overlap = false;
        #pragma unroll
        for (int j = 1; j < NB_; ++j)
            #pragma unroll
            for (int i = 0; i < j; ++i) {
                const int dd = ((baseA[j] - baseA[i] + 128) & 255) - 128;
                ddm[j][i] = dd;
                overlap = overlap || (dd >= -8 && dd <= 8);
            }

        // ---- gathers: row kq-4 per group (+row +4 on kq0), b64 packed math
        v2f ctxp2[NB_];
        #pragma unroll
        for (int i = 0; i < NB_; ++i) {
            const int r0 = (baseA[i] + kq - K_) & (P_ - 1);
            const v2f g0 = *(const v2f*)(ring + r0 * RS_ + e0);
            v2f c = v2s(ws[i]) * g0;
            if (kq == 0) {
                const int r2 = (baseA[i] + K_) & (P_ - 1);
                const v2f g2 = *(const v2f*)(ring + r2 * RS_ + e0);
                c = vfma(v2s(w8[i]), g2, c);
            }
            ctxp2[i] = (v2f){redkq8(c[0]), redkq8(c[1])};
        }

        // ---- inp = x_t @ W_in + b_in (packed)
        v2f inp2 = bin2;
        #pragma unroll
        for (int k = 0; k < 8; ++k)
            inp2 = vfma(v2s(xt[k]), wi2[k], inp2);

        float xtn[8];
        if (t + 1 < T_) {
            float4 a0 = ((const float4*)(xb + (t + 1) * 8))[0];
            float4 a1 = ((const float4*)(xb + (t + 1) * 8))[1];
            xtn[0]=a0.x; xtn[1]=a0.y; xtn[2]=a0.z; xtn[3]=a0.w;
            xtn[4]=a1.x; xtn[5]=a1.y; xtn[6]=a1.z; xtn[7]=a1.w;
        } else {
            #pragma unroll
            for (int k = 0; k < 8; ++k) xtn[k] = 0.f;
        }

        v2f sv2[NB_];

        if (!overlap) {
            // ================= FAST PATH: all 4 bots independent =================
            v2f s1v[NB_];
            #pragma unroll
            for (int j = 0; j < NB_; ++j) {
                const v2f pre = (inp2 + pb2[j]) + hid2[j];
                const v2f z   = vfma(v2s(sigc[j]), ctxp2[j], pre);
                s1v[j] = (v2f){fast_tanh(z[0]), fast_tanh(z[1])};
            }
            if (kq == 0) {
                const int si = 17 * w + (s_ << 1);   // e0 + (e0>>4)
                s4[si]     = make_float4(s1v[0][0], s1v[1][0], s1v[2][0], s1v[3][0]);
                s4[si + 1] = make_float4(s1v[0][1], s1v[1][1], s1v[2][1], s1v[3][1]);
            }
            lgkm_barrier();                         // ONE barrier for all 4 broadcasts

            v2f ab0 = (v2f){0.f, 0.f}, ab1 = ab0, ab2 = ab0, ab3 = ab0;
            const float4* sp = s4 + kq * 17;        // padded: idx(16kq+kk)=17kq+kk
            #pragma unroll
            for (int kk = 0; kk < 16; ++kk) {
                const float4 sq = sp[kk];
                const v2f w2 = wp2[kk];
                ab0 = vfma(v2s(sq.x), w2, ab0);
                ab1 = vfma(v2s(sq.y), w2, ab1);
                ab2 = vfma(v2s(sq.z), w2, ab2);
                ab3 = vfma(v2s(sq.w), w2, ab3);
            }
            sv2[0] = (v2f){fast_tanh(redkq8(ab0[0]) + bp2[0]), fast_tanh(redkq8(ab0[1]) + bp2[1])};
            sv2[1] = (v2f){fast_tanh(redkq8(ab1[0]) + bp2[0]), fast_tanh(redkq8(ab1[1]) + bp2[1])};
            sv2[2] = (v2f){fast_tanh(redkq8(ab2[0]) + bp2[0]), fast_tanh(redkq8(ab2[1]) + bp2[1])};
            sv2[3] = (v2f){fast_tanh(redkq8(ab3[0]) + bp2[0]), fast_tanh(redkq8(ab3[1]) + bp2[1])};
            #pragma unroll
            for (int j = 0; j < NB_; ++j) hid2[j] = sv2[j];

            // disjoint b64 scatters: lane owns row kq-4 (+row +4 on kq0)
            #pragma unroll
            for (int j = 0; j < NB_; ++j) {
                const v2f s = sv2[j];
                const int r0 = (baseA[j] + kq - K_) & (P_ - 1);
                v2f* q0 = (v2f*)(ring + r0 * RS_ + e0);
                *q0 = vfma(v2s(ws[j]), s, *q0);
                if (kq == 0) {
                    const int r2 = (baseA[j] + K_) & (P_ - 1);
                    v2f* q2 = (v2f*)(ring + r2 * RS_ + e0);
                    *q2 = vfma(v2s(w8[j]), s, *q2);
                }
            }
        } else {
            // ================= SLOW PATH: serial chain with coef corrections =====
            float fA[NB_], psinv[NB_];
            fA[0] = dpp_bcast4<0>(f_own); fA[1] = dpp_bcast4<1>(f_own);
            fA[2] = dpp_bcast4<2>(f_own); fA[3] = dpp_bcast4<3>(f_own);
            psinv[0] = dpp_bcast4<0>(psinv_own); psinv[1] = dpp_bcast4<1>(psinv_own);
            psinv[2] = dpp_bcast4<2>(psinv_own); psinv[3] = dpp_bcast4<3>(psinv_own);

            float coefm[NB_][NB_];
            #pragma unroll
            for (int j = 1; j < NB_; ++j) {
                #pragma unroll
                for (int i = 0; i < j; ++i) {
                    const int dd = ddm[j][i];
                    float c = 0.f;
                    if (dd >= -8 && dd <= 8) {
                        const float A = (float)dd - fA[i];
                        const float s  = __expf(-0.25f * (A - fA[j]));
                        const float G  = __expf(0.125f * (fA[i] * fA[i] - A * A));
                        const float s2p = s * s, s3p = s2p * s, s4p = s2p * s2p;
                        const float si = rcpf(s), si2 = si * si, si3 = si2 * si, si4 = si2 * si2;
                        float acc = 0.f;
                        acc += (dd >= 0)              ? Dw4 * si4 : 0.f;
                        acc += (dd >= -1 && dd <= 7)  ? Dw3 * si3 : 0.f;
                        acc += (dd >= -2 && dd <= 6)  ? Dw2 * si2 : 0.f;
                        acc += (dd >= -3 && dd <= 5)  ? Dw1 * si  : 0.f;
                        acc += (dd >= -4 && dd <= 4)  ? 1.0f      : 0.f;
                        acc += (dd >= -5 && dd <= 3)  ? Dw1 * s   : 0.f;
                        acc += (dd >= -6 && dd <= 2)  ? Dw2 * s2p : 0.f;
                        acc += (dd >= -7 && dd <= 1)  ? Dw3 * s3p : 0.f;
                        acc += (dd <= 0)              ? Dw4 * s4p : 0.f;
                        c = psinv[i] * psinv[j] * G * acc;
                    }
                    coefm[j][i] = c;
                }
            }

            #pragma unroll
            for (int j = 0; j < NB_; ++j) {
                v2f ctx = ctxp2[j];
                #pragma unroll
                for (int i = 0; i < j; ++i)
                    ctx = vfma(v2s(coefm[j][i]), sv2[i], ctx);
                const v2f pre = (inp2 + pb2[j]) + hid2[j];
                const v2f z   = vfma(v2s(sigc[j]), ctx, pre);
                const v2f s1  = (v2f){fast_tanh(z[0]), fast_tanh(z[1])};
                if (kq == 0) {
                    const int pf = 20 * w + (s_ << 1);   // e0 + 4*(e0>>4)
                    *(v2f*)(&sbuf[j & 1][pf]) = s1;
                }
                lgkm_barrier();                     // s broadcast ready

                const float4* sp4 = (const float4*)(&sbuf[j & 1][0]);
                v2f axy = (v2f){0.f, 0.f};
                #pragma unroll
                for (int m = 0; m < 4; ++m) {
                    const float4 sq = sp4[5 * kq + m];   // padded: fidx(4kq+m)=5kq+m
                    axy = vfma(v2s(sq.x), wp2[4*m+0], axy);
                    axy = vfma(v2s(sq.y), wp2[4*m+1], axy);
                    axy = vfma(v2s(sq.z), wp2[4*m+2], axy);
                    axy = vfma(v2s(sq.w), wp2[4*m+3], axy);
                }
                v2f s2;
                s2[0] = fast_tanh(redkq8(axy[0]) + bp2[0]);
                s2[1] = fast_tanh(redkq8(axy[1]) + bp2[1]);
                sv2[j] = s2; hid2[j] = s2;

                const int r0 = (baseA[j] + kq - K_) & (P_ - 1);
                v2f* q0 = (v2f*)(ring + r0 * RS_ + e0);
                *q0 = vfma(v2s(ws[j]), s2, *q0);
                if (kq == 0) {
                    const int r2 = (baseA[j] + K_) & (P_ - 1);
                    v2f* q2 = (v2f*)(ring + r2 * RS_ + e0);
                    *q2 = vfma(v2s(w8[j]), s2, *q2);
                }
            }
        }

        // ---- jump dots: per-lane pair dot, reduce the 8 pair slots on VALU
        {
            float vj0 = fmaf(sv2[0][1], jw2[0][1], sv2[0][0] * jw2[0][0]);
            float vj1 = fmaf(sv2[1][1], jw2[1][1], sv2[1][0] * jw2[1][0]);
            float vj2 = fmaf(sv2[2][1], jw2[2][1], sv2[2][0] * jw2[2][0]);
            float vj3 = fmaf(sv2[3][1], jw2[3][1], sv2[3][0] * jw2[3][0]);
            vj0 = redpair(vj0); vj1 = redpair(vj1); vj2 = redpair(vj2); vj3 = redpair(vj3);
            if (l == 0)
                ((float4*)red)[w] = make_float4(vj0, vj1, vj2, vj3);
        }

        // ---- ssum -> history ring (kq0 lanes, b64, packed adds)
        {
            const v2f ssum2 = (sv2[0] + sv2[1]) + (sv2[2] + sv2[3]);
            if (kq == 0) *(v2f*)(&hist[t & 15][e0]) = ssum2;
        }

        lgkm_barrier();                             // scatters + red + hist visible

        // ---- zz combine: 1 b32 read + DPP tree (lane l holds red[4w'+bot])
        {
            float rv = red[l & 31];
            rv = dpp_addf<0x124>(rv);               // row_ror:4 -> + same-bot, w'+1
            rv = dpp_addf<0x128>(rv);               // row_ror:8 -> all w' in 16-row
            rv = pl16_sum(rv);                      // + other 16-row
            const float zz0 = dpp_bcast4<0>(rv) + jb_r[0];
            const float zz1 = dpp_bcast4<1>(rv) + jb_r[1];
            const float zz2 = dpp_bcast4<2>(rv) + jb_r[2];
            const float zz3 = dpp_bcast4<3>(rv) + jb_r[3];
            const float zz[4] = { zz0, zz1, zz2, zz3 };
            #pragma unroll
            for (int i = 0; i < NB_; ++i) {
                float np;
                if (zz[i] > 0.0f) np = jt[i];
                else { np = ptrv[i] + 1.0f; if (np >= 256.0f) np -= 256.0f; }
                ptrv[i] = np;
            }
        }

        // ---- every 8th step: out dots spread over all 8 waves
        // wave w -> history row tt=w; lane: m = l>>3, chunk c4 = l&7 (4 float4s);
        // redpair sums the 8 chunks; lane (l&7)==0 stores. Reordered 128-sum is
        // output-only (error ~1e-6 << threshold).
        if ((t & 7) == 7) {
            const int tt = w;
            const int m  = l >> 3;
            const int c4 = l & 7;
            const float* hrow = hist[(t - 7 + tt) & 15];
            const float* wrow = wout_s[m];
            float acc = 0.f;
            #pragma unroll
            for (int q = 0; q < 4; ++q) {
                const float4 h4 = ((const float4*)hrow)[c4 * 4 + q];
                const float4 w4 = ((const float4*)wrow)[c4 * 4 + q];
                acc += ((h4.x * w4.x + h4.y * w4.y) + (h4.z * w4.z + h4.w * w4.w));
            }
            acc = redpair(acc);
            if ((l & 7) == 0)
                out[((size_t)b * T_ + (t - 7 + tt)) * 8 + m] = acc + bout_m;
        }

        #pragma unroll
        for (int k = 0; k < 8; ++k) xt[k] = xtn[k];
    }
}

extern "C" void kernel_launch(void* const* d_in, const int* in_sizes, int n_in,
                              void* d_out, int out_size, void* d_ws, size_t ws_size,
                              hipStream_t stream) {
    (void)in_sizes; (void)n_in; (void)out_size; (void)d_ws; (void)ws_size;
    swarm_ring_kernel<<<dim3(B_), dim3(512), 0, stream>>>(
        (const float*)d_in[0],  (const float*)d_in[1],  (const float*)d_in[2],
        (const float*)d_in[3],  (const float*)d_in[4],  (const float*)d_in[5],
        (const float*)d_in[6],  (const float*)d_in[7],  (const float*)d_in[8],
        (const float*)d_in[9],  (const float*)d_in[10], (const float*)d_in[11],
        (const float*)d_in[12], (float*)d_out);
}